// Round 6
// baseline (1177.037 us; speedup 1.0000x reference)
//
#include <hip/hip_runtime.h>
#include <hip/hip_bf16.h>
#include <cstdint>
#include <cstddef>

#define TLEN 2048
#define NB 2
#define DMODEL 1024
#define NH 16
#define NDH 64

typedef unsigned short ushortT;
typedef short bf16x8 __attribute__((ext_vector_type(8)));
typedef float f32x16 __attribute__((ext_vector_type(16)));

__device__ __forceinline__ ushortT f2bf(float f) {
  union { float f; unsigned int u; } x{f};
  unsigned int r = x.u + 0x7fff + ((x.u >> 16) & 1);   // RNE
  return (ushortT)(r >> 16);
}
__device__ __forceinline__ unsigned int pk2(float lo, float hi) {
  return ((unsigned int)f2bf(hi) << 16) | (unsigned int)f2bf(lo);
}
__device__ __forceinline__ float bf2f(ushortT u) {
  union { unsigned int u; float f; } x;
  x.u = ((unsigned int)u) << 16;
  return x.f;
}

__device__ __forceinline__ void gld_lds16(const void* g, void* l) {
  __builtin_amdgcn_global_load_lds(
      (const __attribute__((address_space(1))) unsigned int*)g,
      (__attribute__((address_space(3))) unsigned int*)l, 16, 0, 0);
}

// ---------------------------------------------------------------------------
// converts
// ---------------------------------------------------------------------------

__global__ __launch_bounds__(256) void cvt_bf16(const float* __restrict__ in,
                                                ushortT* __restrict__ out, int n4) {
  int i = blockIdx.x * 256 + threadIdx.x;
  if (i < n4) {
    float4 v = reinterpret_cast<const float4*>(in)[i];
    ushort4 o;
    o.x = f2bf(v.x); o.y = f2bf(v.y); o.z = f2bf(v.z); o.w = f2bf(v.w);
    reinterpret_cast<ushort4*>(out)[i] = o;
  }
}

__global__ __launch_bounds__(256) void cvt_mask(const int* __restrict__ mask,
                                                float* __restrict__ mfl) {
  int j = blockIdx.x * 256 + threadIdx.x;
  if (j < TLEN) {
    mfl[j]        = mask[j * NB]     ? 0.f : 1.f;
    mfl[TLEN + j] = mask[j * NB + 1] ? 0.f : 1.f;
  }
}

// ---------------------------------------------------------------------------
// bf16 MFMA GEMM (unchanged from round 4)
// ---------------------------------------------------------------------------

template <typename Epi>
__global__ __launch_bounds__(256) void gemm_bf16(const ushortT* __restrict__ A,
                                                 const ushortT* __restrict__ B,
                                                 int K, Epi epi) {
  __shared__ ushortT Al[128 * 64];
  __shared__ ushortT Bl[128 * 64];
  const int tid = threadIdx.x;
  const int lane = tid & 63;
  const int wv = tid >> 6;
  const int wm = wv >> 1, wn = wv & 1;
  const int m0 = blockIdx.y * 128;
  const int n0 = blockIdx.x * 128;
  const int r32 = lane & 31;
  const int hh = lane >> 5;

  f32x16 acc[2][2];
#pragma unroll
  for (int i = 0; i < 2; ++i)
#pragma unroll
    for (int j = 0; j < 2; ++j)
#pragma unroll
      for (int e = 0; e < 16; ++e) acc[i][j][e] = 0.f;

  for (int k0 = 0; k0 < K; k0 += 64) {
#pragma unroll
    for (int it = 0; it < 4; ++it) {
      int idx = it * 256 + tid;          // 1024 chunks of 16B
      int r = idx >> 3, c = idx & 7;
      int gcol = k0 + ((c ^ (r & 7)) << 3);
      gld_lds16(A + (size_t)(m0 + r) * K + gcol, Al + idx * 8);
      gld_lds16(B + (size_t)(n0 + r) * K + gcol, Bl + idx * 8);
    }
    asm volatile("s_waitcnt vmcnt(0)");
    __syncthreads();
#pragma unroll
    for (int kc = 0; kc < 4; ++kc) {
      int lc = kc * 2 + hh;              // logical 16B chunk in row
      bf16x8 af[2], bfr[2];
#pragma unroll
      for (int f = 0; f < 2; ++f) {
        int ar = wm * 64 + f * 32 + r32;
        af[f] = *(const bf16x8*)(Al + ar * 64 + ((lc ^ (ar & 7)) << 3));
        int br = wn * 64 + f * 32 + r32;
        bfr[f] = *(const bf16x8*)(Bl + br * 64 + ((lc ^ (br & 7)) << 3));
      }
#pragma unroll
      for (int i = 0; i < 2; ++i)
#pragma unroll
        for (int j = 0; j < 2; ++j)
          acc[i][j] = __builtin_amdgcn_mfma_f32_32x32x16_bf16(af[i], bfr[j],
                                                              acc[i][j], 0, 0, 0);
    }
    __syncthreads();
  }

#pragma unroll
  for (int i = 0; i < 2; ++i)
#pragma unroll
    for (int j = 0; j < 2; ++j)
#pragma unroll
      for (int rg = 0; rg < 16; ++rg) {
        int m = m0 + wm * 64 + i * 32 + (rg & 3) + 8 * (rg >> 2) + 4 * hh;
        int n = n0 + wn * 64 + j * 32 + r32;
        epi.store(m, n, acc[i][j][rg]);
      }
}

struct EpiQKV {
  ushortT* qb; ushortT* kb; ushortT* vtb; const float* bias;
  __device__ void store(int m, int n, float val) const {
    int t = m >> 1, b = m & 1;
    int which = n >> 10;
    int h = (n >> 6) & (NH - 1);
    int dh = n & (NDH - 1);
    int bh = b * NH + h;
    if (which == 0)
      qb[((size_t)bh * TLEN + t) * NDH + dh] = f2bf(val + bias[(h << 6) | dh]);
    else if (which == 1)
      kb[((size_t)bh * TLEN + t) * NDH + dh] = f2bf(val);
    else
      vtb[((size_t)bh * NDH + dh) * TLEN + t] = f2bf(val);
  }
};

struct EpiRK {
  ushortT* rk;
  __device__ void store(int m, int n, float val) const {
    int h = n >> 6, dh = n & 63;
    rk[((size_t)h * TLEN + m) * NDH + dh] = f2bf(val);
  }
};

struct EpiOut {
  float* out;
  __device__ void store(int m, int n, float val) const {
    out[(size_t)m * DMODEL + n] = val;
  }
};

// ---------------------------------------------------------------------------
// MFMA attention, j-split for occupancy.
// Grid (32, 32): blockIdx.y = bh, blockIdx.x = 64-q-row group.
// Block = 4 waves: wave wv -> q-tile (wv&1) of 32 rows, j-half (wv>>1).
// 1024 blocks = 4 blocks/CU = 16 waves/CU. Per 32-j chunk, 2 rel-shift
// window tiles (see round-4 derivation); p~ bf16 to prob upper-half slots
// (disjoint j ranges across waves); l & PV combined across j-halves via W
// LDS buffer + one barrier at the end.
// ---------------------------------------------------------------------------

__global__ __launch_bounds__(256, 4) void attn_mfma(
    const ushortT* __restrict__ qb, const ushortT* __restrict__ kb,
    const ushortT* __restrict__ vtb, const ushortT* __restrict__ rkb,
    const float* __restrict__ mfl, float* __restrict__ prob,
    float* __restrict__ l_s, ushortT* __restrict__ av_bf) {
  __shared__ float W[4][64][32];
  __shared__ float sl[4][32];

  const int bh = blockIdx.y;
  const int b = bh >> 4, h = bh & 15;
  const int wv = threadIdx.x >> 6;
  const int lane = threadIdx.x & 63;
  const int ql = lane & 31;
  const int hh = lane >> 5;
  const int q0 = blockIdx.x * 64 + (wv & 1) * 32;
  const int jh = wv >> 1;
  const int qg = q0 + ql;

  const ushortT* Qbh = qb + (size_t)bh * TLEN * NDH;
  const ushortT* Kbh = kb + (size_t)bh * TLEN * NDH;
  const ushortT* Vbh = vtb + (size_t)bh * NDH * TLEN;
  const ushortT* Rh  = rkb + (size_t)h * TLEN * NDH;
  const float* mflb  = mfl + (size_t)b * TLEN;
  float (*Wp)[32] = W[wv];

  bf16x8 Qf[4], Qs[4];
  {
    int r2 = min(qg + 1, TLEN - 1);
#pragma unroll
    for (int c = 0; c < 4; ++c) {
      Qf[c] = *(const bf16x8*)(Qbh + (size_t)qg * NDH + c * 16 + hh * 8);
      Qs[c] = *(const bf16x8*)(Qbh + (size_t)r2 * NDH + c * 16 + hh * 8);
    }
  }

  f32x16 pacc0, pacc1;
#pragma unroll
  for (int i = 0; i < 16; ++i) { pacc0[i] = 0.f; pacc1[i] = 0.f; }
  float l_acc = 0.f;

  ushortT* pbrow = (ushortT*)prob + ((size_t)bh * TLEN + qg) * 4096 + 2048;

  const int jbeg = jh * (TLEN / 2);
  const int jend = jbeg + (TLEN / 2);
  for (int j0 = jbeg; j0 < jend; j0 += 32) {
    const int w1b = 2016 - q0 + j0;
    const int w2b = j0 - q0 - 33;
    const int base0 = (j0 <= q0) ? w1b : w2b;
    const int base1 = ((j0 < q0) ? w1b : w2b) + 32;
    const bool t0w1 = (j0 <= q0);
    const bool t1w1 = (j0 < q0);

    // loads for this chunk
    int r0 = max(0, min(base0 + ql, TLEN - 1));
    int r1 = max(0, min(base1 + ql, TLEN - 1));
    const ushortT* s0 = Rh + (size_t)r0 * NDH + hh * 8;
    const ushortT* s1 = Rh + (size_t)r1 * NDH + hh * 8;
    const ushortT* sk = Kbh + (size_t)(j0 + ql) * NDH + hh * 8;
    const ushortT* vrow0 = Vbh + (size_t)ql * TLEN + j0 + 8 * hh;
    const ushortT* vrow1 = Vbh + (size_t)(32 + ql) * TLEN + j0 + 8 * hh;
    bf16x8 rk0[4], rk1[4], kk[4];
#pragma unroll
    for (int c = 0; c < 4; ++c) {
      rk0[c] = *(const bf16x8*)(s0 + c * 16);
      rk1[c] = *(const bf16x8*)(s1 + c * 16);
      kk[c]  = *(const bf16x8*)(sk + c * 16);
    }
    bf16x8 v00 = *(const bf16x8*)(vrow0);
    bf16x8 v01 = *(const bf16x8*)(vrow0 + 16);
    bf16x8 v10 = *(const bf16x8*)(vrow1);
    bf16x8 v11 = *(const bf16x8*)(vrow1 + 16);
    float4 mf4[4];
#pragma unroll
    for (int g = 0; g < 4; ++g)
      mf4[g] = *(const float4*)(mflb + j0 + 8 * g + 4 * hh);

    f32x16 f0, f1, cacc;
#pragma unroll
    for (int i = 0; i < 16; ++i) { f0[i] = 0.f; f1[i] = 0.f; cacc[i] = 0.f; }

    __builtin_amdgcn_s_setprio(1);
#pragma unroll
    for (int c = 0; c < 4; ++c)
      f0 = __builtin_amdgcn_mfma_f32_32x32x16_bf16(rk0[c], t0w1 ? Qf[c] : Qs[c], f0, 0, 0, 0);
#pragma unroll
    for (int c = 0; c < 4; ++c)
      f1 = __builtin_amdgcn_mfma_f32_32x32x16_bf16(rk1[c], t1w1 ? Qf[c] : Qs[c], f1, 0, 0, 0);
#pragma unroll
    for (int c = 0; c < 4; ++c)
      cacc = __builtin_amdgcn_mfma_f32_32x32x16_bf16(kk[c], Qf[c], cacc, 0, 0, 0);
    __builtin_amdgcn_s_setprio(0);

#pragma unroll
    for (int r = 0; r < 16; ++r) {
      Wp[(r & 3) + 8 * (r >> 2) + 4 * hh][ql] = f0[r];
      Wp[32 + (r & 3) + 8 * (r >> 2) + 4 * hh][ql] = f1[r];
    }

    float p[16];
#pragma unroll
    for (int r = 0; r < 16; ++r) {
      int jrow = (r & 3) + 8 * (r >> 2) + 4 * hh;
      int jg = j0 + jrow;
      float bd = (jg == qg + 1) ? 0.f : Wp[jrow - ql + 31][ql];
      float sc = (cacc[r] + bd) * 0.125f;
      float mv = (&mf4[r >> 2].x)[r & 3];
      float pv = mv * __expf(sc);
      p[r] = pv;
      l_acc += pv;
    }

#pragma unroll
    for (int g = 0; g < 4; ++g) {
      uint2 st;
      st.x = pk2(p[4 * g + 0], p[4 * g + 1]);
      st.y = pk2(p[4 * g + 2], p[4 * g + 3]);
      *reinterpret_cast<uint2*>(pbrow + j0 + 8 * g + 4 * hh) = st;
    }

#pragma unroll
    for (int kh = 0; kh < 2; ++kh) {
      unsigned int u0 = pk2(p[8 * kh + 0], p[8 * kh + 1]);
      unsigned int u1 = pk2(p[8 * kh + 2], p[8 * kh + 3]);
      unsigned int u2 = pk2(p[8 * kh + 4], p[8 * kh + 5]);
      unsigned int u3 = pk2(p[8 * kh + 6], p[8 * kh + 7]);
      unsigned int t0 = (unsigned int)__shfl_xor((int)u0, 32);
      unsigned int t1 = (unsigned int)__shfl_xor((int)u1, 32);
      unsigned int t2 = (unsigned int)__shfl_xor((int)u2, 32);
      unsigned int t3 = (unsigned int)__shfl_xor((int)u3, 32);
      unsigned int fr[4];
      fr[0] = hh ? t2 : u0;
      fr[1] = hh ? t3 : u1;
      fr[2] = hh ? u2 : t0;
      fr[3] = hh ? u3 : t1;
      bf16x8 pa = *reinterpret_cast<bf16x8*>(fr);
      __builtin_amdgcn_s_setprio(1);
      pacc0 = __builtin_amdgcn_mfma_f32_32x32x16_bf16(pa, kh ? v01 : v00, pacc0, 0, 0, 0);
      pacc1 = __builtin_amdgcn_mfma_f32_32x32x16_bf16(pa, kh ? v11 : v10, pacc1, 0, 0, 0);
      __builtin_amdgcn_s_setprio(0);
    }
  }

  // ---- cross-j-half reduction via W (wave-private until here) ----
#pragma unroll
  for (int r = 0; r < 16; ++r) {
    int qrow = (r & 3) + 8 * (r >> 2) + 4 * hh;
    Wp[qrow][ql] = pacc0[r];
    Wp[32 + qrow][ql] = pacc1[r];
  }
  float lh = l_acc + __shfl_xor(l_acc, 32);
  if (lane < 32) sl[wv][ql] = lh;
  __syncthreads();

  if (wv < 2) {   // wave wv finalizes q-tile q0 = blockIdx.x*64 + wv*32
    if (lane < 32) {
      float lt = sl[wv][ql] + sl[wv + 2][ql];
      l_s[(size_t)bh * TLEN + q0 + ql] = lt;
    }
#pragma unroll
    for (int r = 0; r < 16; ++r) {
      int qrow = (r & 3) + 8 * (r >> 2) + 4 * hh;
      float lt = sl[wv][qrow] + sl[wv + 2][qrow];
      float iv = 1.0f / lt;
      float s0 = W[wv][qrow][ql] + W[wv + 2][qrow][ql];
      float s1 = W[wv][32 + qrow][ql] + W[wv + 2][32 + qrow][ql];
      size_t aoff = ((size_t)(q0 + qrow) * NB + b) * DMODEL + h * NDH;
      av_bf[aoff + ql] = f2bf(s0 * iv);
      av_bf[aoff + 32 + ql] = f2bf(s1 * iv);
    }
  }
}

// ---------------------------------------------------------------------------
// prob row: read bf16 p~ from upper half of the row's 8KB slot, barrier,
// write f32 p~/l over the whole slot. Row-local overlap only.
// ---------------------------------------------------------------------------

__global__ __launch_bounds__(256) void rescale_kernel(float* __restrict__ prob,
                                                      const float* __restrict__ l_s) {
  const int row = blockIdx.x;
  const float inv = 1.0f / l_s[row];
  const int t = threadIdx.x;
  const ushortT* src = (const ushortT*)prob + (size_t)row * 4096 + 2048 + t * 8;
  uint4 u = *reinterpret_cast<const uint4*>(src);
  __syncthreads();
  float o[8];
  o[0] = bf2f((ushortT)(u.x & 0xffff)) * inv;
  o[1] = bf2f((ushortT)(u.x >> 16)) * inv;
  o[2] = bf2f((ushortT)(u.y & 0xffff)) * inv;
  o[3] = bf2f((ushortT)(u.y >> 16)) * inv;
  o[4] = bf2f((ushortT)(u.z & 0xffff)) * inv;
  o[5] = bf2f((ushortT)(u.z >> 16)) * inv;
  o[6] = bf2f((ushortT)(u.w & 0xffff)) * inv;
  o[7] = bf2f((ushortT)(u.w >> 16)) * inv;
  float4* dst = reinterpret_cast<float4*>(prob + (size_t)row * 2048 + t * 8);
  dst[0] = make_float4(o[0], o[1], o[2], o[3]);
  dst[1] = make_float4(o[4], o[5], o[6], o[7]);
}

// ---------------------------------------------------------------------------

extern "C" void kernel_launch(void* const* d_in, const int* in_sizes, int n_in,
                              void* d_out, int out_size, void* d_ws, size_t ws_size,
                              hipStream_t stream) {
  const float* w      = (const float*)d_in[0];   // (T,B,D)
  const float* r      = (const float*)d_in[1];   // (T,D)
  const float* w_qkv  = (const float*)d_in[2];   // (3072,1024)
  const float* w_r    = (const float*)d_in[3];   // (1024,1024)
  const float* w_o    = (const float*)d_in[4];   // (1024,1024)
  const float* bias   = (const float*)d_in[5];   // (16,64)
  const int* mask     = (const int*)d_in[6];     // (T,B) int32

  float* out  = (float*)d_out;
  float* prob = out + (size_t)TLEN * NB * DMODEL;

  const size_t SZ = (size_t)NB * NH * TLEN * NDH;        // 4194304
  ushortT* w_bf    = (ushortT*)d_ws;
  ushortT* wqkv_bf = w_bf + (size_t)4096 * 1024;
  ushortT* r_bf    = wqkv_bf + (size_t)3072 * 1024;
  ushortT* wr_bf   = r_bf + (size_t)2048 * 1024;
  ushortT* wo_bf   = wr_bf + (size_t)1024 * 1024;
  ushortT* q_bf    = wo_bf + (size_t)1024 * 1024;
  ushortT* k_bf    = q_bf + SZ;
  ushortT* vt_bf   = k_bf + SZ;
  ushortT* rk_bf   = vt_bf + SZ;
  ushortT* av_bf   = rk_bf + SZ / 2;
  float* l_s       = (float*)(av_bf + SZ);
  float* mfl       = l_s + (size_t)NB * NH * TLEN;

  cvt_bf16<<<4096, 256, 0, stream>>>(w, w_bf, 4096 * 1024 / 4);
  cvt_bf16<<<3072, 256, 0, stream>>>(w_qkv, wqkv_bf, 3072 * 1024 / 4);
  cvt_bf16<<<2048, 256, 0, stream>>>(r, r_bf, 2048 * 1024 / 4);
  cvt_bf16<<<1024, 256, 0, stream>>>(w_r, wr_bf, 1024 * 1024 / 4);
  cvt_bf16<<<1024, 256, 0, stream>>>(w_o, wo_bf, 1024 * 1024 / 4);
  cvt_mask<<<8, 256, 0, stream>>>(mask, mfl);

  EpiQKV e1{q_bf, k_bf, vt_bf, bias};
  gemm_bf16<EpiQKV><<<dim3(3072 / 128, 4096 / 128), 256, 0, stream>>>(w_bf, wqkv_bf, DMODEL, e1);
  EpiRK e2{rk_bf};
  gemm_bf16<EpiRK><<<dim3(1024 / 128, 2048 / 128), 256, 0, stream>>>(r_bf, wr_bf, DMODEL, e2);

  attn_mfma<<<dim3(32, 32), 256, 0, stream>>>(q_bf, k_bf, vt_bf, rk_bf,
                                              mfl, prob, l_s, av_bf);
  rescale_kernel<<<dim3(NB * NH * TLEN), 256, 0, stream>>>(prob, l_s);

  EpiOut e5{out};
  gemm_bf16<EpiOut><<<dim3(1024 / 128, 4096 / 128), 256, 0, stream>>>(av_bf, wo_bf, DMODEL, e5);
}

// Round 7
// 589.952 us; speedup vs baseline: 1.9951x; 1.9951x over previous
//
#include <hip/hip_runtime.h>
#include <hip/hip_bf16.h>
#include <cstdint>
#include <cstddef>

#define TLEN 2048
#define NB 2
#define DMODEL 1024
#define NH 16
#define NDH 64

typedef unsigned short ushortT;
typedef short bf16x8 __attribute__((ext_vector_type(8)));
typedef float f32x16 __attribute__((ext_vector_type(16)));

__device__ __forceinline__ ushortT f2bf(float f) {
  union { float f; unsigned int u; } x{f};
  unsigned int r = x.u + 0x7fff + ((x.u >> 16) & 1);   // RNE
  return (ushortT)(r >> 16);
}
__device__ __forceinline__ unsigned int pk2(float lo, float hi) {
  return ((unsigned int)f2bf(hi) << 16) | (unsigned int)f2bf(lo);
}
__device__ __forceinline__ float bf2f(ushortT u) {
  union { unsigned int u; float f; } x;
  x.u = ((unsigned int)u) << 16;
  return x.f;
}

__device__ __forceinline__ void gld_lds16(const void* g, void* l) {
  __builtin_amdgcn_global_load_lds(
      (const __attribute__((address_space(1))) unsigned int*)g,
      (__attribute__((address_space(3))) unsigned int*)l, 16, 0, 0);
}

// ---------------------------------------------------------------------------
// converts
// ---------------------------------------------------------------------------

__global__ __launch_bounds__(256) void cvt_bf16(const float* __restrict__ in,
                                                ushortT* __restrict__ out, int n4) {
  int i = blockIdx.x * 256 + threadIdx.x;
  if (i < n4) {
    float4 v = reinterpret_cast<const float4*>(in)[i];
    ushort4 o;
    o.x = f2bf(v.x); o.y = f2bf(v.y); o.z = f2bf(v.z); o.w = f2bf(v.w);
    reinterpret_cast<ushort4*>(out)[i] = o;
  }
}

__global__ __launch_bounds__(256) void cvt_mask(const int* __restrict__ mask,
                                                float* __restrict__ mfl) {
  int j = blockIdx.x * 256 + threadIdx.x;
  if (j < TLEN) {
    mfl[j]        = mask[j * NB]     ? 0.f : 1.f;
    mfl[TLEN + j] = mask[j * NB + 1] ? 0.f : 1.f;
  }
}

// ---------------------------------------------------------------------------
// bf16 MFMA GEMM (unchanged from round 4)
// ---------------------------------------------------------------------------

template <typename Epi>
__global__ __launch_bounds__(256) void gemm_bf16(const ushortT* __restrict__ A,
                                                 const ushortT* __restrict__ B,
                                                 int K, Epi epi) {
  __shared__ ushortT Al[128 * 64];
  __shared__ ushortT Bl[128 * 64];
  const int tid = threadIdx.x;
  const int lane = tid & 63;
  const int wv = tid >> 6;
  const int wm = wv >> 1, wn = wv & 1;
  const int m0 = blockIdx.y * 128;
  const int n0 = blockIdx.x * 128;
  const int r32 = lane & 31;
  const int hh = lane >> 5;

  f32x16 acc[2][2];
#pragma unroll
  for (int i = 0; i < 2; ++i)
#pragma unroll
    for (int j = 0; j < 2; ++j)
#pragma unroll
      for (int e = 0; e < 16; ++e) acc[i][j][e] = 0.f;

  for (int k0 = 0; k0 < K; k0 += 64) {
#pragma unroll
    for (int it = 0; it < 4; ++it) {
      int idx = it * 256 + tid;          // 1024 chunks of 16B
      int r = idx >> 3, c = idx & 7;
      int gcol = k0 + ((c ^ (r & 7)) << 3);
      gld_lds16(A + (size_t)(m0 + r) * K + gcol, Al + idx * 8);
      gld_lds16(B + (size_t)(n0 + r) * K + gcol, Bl + idx * 8);
    }
    asm volatile("s_waitcnt vmcnt(0)");
    __syncthreads();
#pragma unroll
    for (int kc = 0; kc < 4; ++kc) {
      int lc = kc * 2 + hh;              // logical 16B chunk in row
      bf16x8 af[2], bfr[2];
#pragma unroll
      for (int f = 0; f < 2; ++f) {
        int ar = wm * 64 + f * 32 + r32;
        af[f] = *(const bf16x8*)(Al + ar * 64 + ((lc ^ (ar & 7)) << 3));
        int br = wn * 64 + f * 32 + r32;
        bfr[f] = *(const bf16x8*)(Bl + br * 64 + ((lc ^ (br & 7)) << 3));
      }
#pragma unroll
      for (int i = 0; i < 2; ++i)
#pragma unroll
        for (int j = 0; j < 2; ++j)
          acc[i][j] = __builtin_amdgcn_mfma_f32_32x32x16_bf16(af[i], bfr[j],
                                                              acc[i][j], 0, 0, 0);
    }
    __syncthreads();
  }

#pragma unroll
  for (int i = 0; i < 2; ++i)
#pragma unroll
    for (int j = 0; j < 2; ++j)
#pragma unroll
      for (int rg = 0; rg < 16; ++rg) {
        int m = m0 + wm * 64 + i * 32 + (rg & 3) + 8 * (rg >> 2) + 4 * hh;
        int n = n0 + wn * 64 + j * 32 + r32;
        epi.store(m, n, acc[i][j][rg]);
      }
}

struct EpiQKV {
  ushortT* qb; ushortT* kb; ushortT* vtb; const float* bias;
  __device__ void store(int m, int n, float val) const {
    int t = m >> 1, b = m & 1;
    int which = n >> 10;
    int h = (n >> 6) & (NH - 1);
    int dh = n & (NDH - 1);
    int bh = b * NH + h;
    if (which == 0)
      qb[((size_t)bh * TLEN + t) * NDH + dh] = f2bf(val + bias[(h << 6) | dh]);
    else if (which == 1)
      kb[((size_t)bh * TLEN + t) * NDH + dh] = f2bf(val);
    else
      vtb[((size_t)bh * NDH + dh) * TLEN + t] = f2bf(val);
  }
};

struct EpiRK {
  ushortT* rk;
  __device__ void store(int m, int n, float val) const {
    int h = n >> 6, dh = n & 63;
    rk[((size_t)h * TLEN + m) * NDH + dh] = f2bf(val);
  }
};

struct EpiOut {
  float* out;
  __device__ void store(int m, int n, float val) const {
    out[(size_t)m * DMODEL + n] = val;
  }
};

// ---------------------------------------------------------------------------
// MFMA attention, j-split + fused rescale.
// Grid (32, 32): blockIdx.y = bh, blockIdx.x = 64-q-row group.
// Block = 4 waves: wave wv -> q-tile (wv&1), j-half (wv>>1). Plain
// launch_bounds (R6 lesson: forcing min-waves caused a 64-VGPR clamp and
// massive scratch spills). Per 32-j chunk, 2 rel-shift window tiles; one
// reused facc register block (serialized through W) keeps pressure down.
// p~ bf16 staged into upper half of each prob row slot; after the l
// reduction the SAME block re-reads its staging (L2-hot) and writes the
// normalized f32 prob in 8 row-stripes with a barrier between stripe
// reads and stripe writes (jh=1's f32 writes overlap jh=0's staging).
// ---------------------------------------------------------------------------

__global__ __launch_bounds__(256) void attn_mfma(
    const ushortT* __restrict__ qb, const ushortT* __restrict__ kb,
    const ushortT* __restrict__ vtb, const ushortT* __restrict__ rkb,
    const float* __restrict__ mfl, float* __restrict__ prob,
    ushortT* __restrict__ av_bf) {
  __shared__ float W[4][64][32];
  __shared__ float sl[4][32];
  __shared__ float linv[64];

  const int bh = blockIdx.y;
  const int b = bh >> 4, h = bh & 15;
  const int wv = threadIdx.x >> 6;
  const int lane = threadIdx.x & 63;
  const int ql = lane & 31;
  const int hh = lane >> 5;
  const int qtile = wv & 1;
  const int jh = wv >> 1;
  const int q0 = blockIdx.x * 64 + qtile * 32;
  const int qg = q0 + ql;

  const ushortT* Qbh = qb + (size_t)bh * TLEN * NDH;
  const ushortT* Kbh = kb + (size_t)bh * TLEN * NDH;
  const ushortT* Vbh = vtb + (size_t)bh * NDH * TLEN;
  const ushortT* Rh  = rkb + (size_t)h * TLEN * NDH;
  const float* mflb  = mfl + (size_t)b * TLEN;
  float (*Wp)[32] = W[wv];

  bf16x8 Qf[4], Qs[4];
  {
    int r2 = min(qg + 1, TLEN - 1);
#pragma unroll
    for (int c = 0; c < 4; ++c) {
      Qf[c] = *(const bf16x8*)(Qbh + (size_t)qg * NDH + c * 16 + hh * 8);
      Qs[c] = *(const bf16x8*)(Qbh + (size_t)r2 * NDH + c * 16 + hh * 8);
    }
  }

  f32x16 pacc0, pacc1;
#pragma unroll
  for (int i = 0; i < 16; ++i) { pacc0[i] = 0.f; pacc1[i] = 0.f; }
  float l_acc = 0.f;

  ushortT* pbrow = (ushortT*)prob + ((size_t)bh * TLEN + qg) * 4096 + 2048;

  const int jbeg = jh * (TLEN / 2);
  const int jend = jbeg + (TLEN / 2);
  for (int j0 = jbeg; j0 < jend; j0 += 32) {
    const int w1b = 2016 - q0 + j0;
    const int w2b = j0 - q0 - 33;
    const int base0 = (j0 <= q0) ? w1b : w2b;
    const int base1 = ((j0 < q0) ? w1b : w2b) + 32;
    const bool t0w1 = (j0 <= q0);
    const bool t1w1 = (j0 < q0);

    int r0 = max(0, min(base0 + ql, TLEN - 1));
    int r1 = max(0, min(base1 + ql, TLEN - 1));
    const ushortT* s0 = Rh + (size_t)r0 * NDH + hh * 8;
    const ushortT* s1 = Rh + (size_t)r1 * NDH + hh * 8;
    const ushortT* sk = Kbh + (size_t)(j0 + ql) * NDH + hh * 8;
    const ushortT* vrow0 = Vbh + (size_t)ql * TLEN + j0 + 8 * hh;
    const ushortT* vrow1 = Vbh + (size_t)(32 + ql) * TLEN + j0 + 8 * hh;
    bf16x8 rk0[4], rk1[4], kk[4];
#pragma unroll
    for (int c = 0; c < 4; ++c) {
      rk0[c] = *(const bf16x8*)(s0 + c * 16);
      rk1[c] = *(const bf16x8*)(s1 + c * 16);
      kk[c]  = *(const bf16x8*)(sk + c * 16);
    }
    bf16x8 v00 = *(const bf16x8*)(vrow0);
    bf16x8 v01 = *(const bf16x8*)(vrow0 + 16);
    bf16x8 v10 = *(const bf16x8*)(vrow1);
    bf16x8 v11 = *(const bf16x8*)(vrow1 + 16);
    float4 mf4[4];
#pragma unroll
    for (int g = 0; g < 4; ++g)
      mf4[g] = *(const float4*)(mflb + j0 + 8 * g + 4 * hh);

    // BD window tile 0 -> W rows [0,32)
    f32x16 facc;
#pragma unroll
    for (int i = 0; i < 16; ++i) facc[i] = 0.f;
    __builtin_amdgcn_s_setprio(1);
#pragma unroll
    for (int c = 0; c < 4; ++c)
      facc = __builtin_amdgcn_mfma_f32_32x32x16_bf16(rk0[c], t0w1 ? Qf[c] : Qs[c], facc, 0, 0, 0);
    __builtin_amdgcn_s_setprio(0);
#pragma unroll
    for (int r = 0; r < 16; ++r)
      Wp[(r & 3) + 8 * (r >> 2) + 4 * hh][ql] = facc[r];

    // BD window tile 1 -> W rows [32,64)  (reuse facc)
#pragma unroll
    for (int i = 0; i < 16; ++i) facc[i] = 0.f;
    __builtin_amdgcn_s_setprio(1);
#pragma unroll
    for (int c = 0; c < 4; ++c)
      facc = __builtin_amdgcn_mfma_f32_32x32x16_bf16(rk1[c], t1w1 ? Qf[c] : Qs[c], facc, 0, 0, 0);
    __builtin_amdgcn_s_setprio(0);
#pragma unroll
    for (int r = 0; r < 16; ++r)
      Wp[32 + (r & 3) + 8 * (r >> 2) + 4 * hh][ql] = facc[r];

    // AC tile (S^T)
    f32x16 cacc;
#pragma unroll
    for (int i = 0; i < 16; ++i) cacc[i] = 0.f;
    __builtin_amdgcn_s_setprio(1);
#pragma unroll
    for (int c = 0; c < 4; ++c)
      cacc = __builtin_amdgcn_mfma_f32_32x32x16_bf16(kk[c], Qf[c], cacc, 0, 0, 0);
    __builtin_amdgcn_s_setprio(0);

    float p[16];
#pragma unroll
    for (int r = 0; r < 16; ++r) {
      int jrow = (r & 3) + 8 * (r >> 2) + 4 * hh;
      int jg = j0 + jrow;
      float bd = (jg == qg + 1) ? 0.f : Wp[jrow - ql + 31][ql];
      float sc = (cacc[r] + bd) * 0.125f;
      float mv = (&mf4[r >> 2].x)[r & 3];
      float pv = mv * __expf(sc);
      p[r] = pv;
      l_acc += pv;
    }

#pragma unroll
    for (int g = 0; g < 4; ++g) {
      uint2 st;
      st.x = pk2(p[4 * g + 0], p[4 * g + 1]);
      st.y = pk2(p[4 * g + 2], p[4 * g + 3]);
      *reinterpret_cast<uint2*>(pbrow + j0 + 8 * g + 4 * hh) = st;
    }

#pragma unroll
    for (int kh = 0; kh < 2; ++kh) {
      unsigned int u0 = pk2(p[8 * kh + 0], p[8 * kh + 1]);
      unsigned int u1 = pk2(p[8 * kh + 2], p[8 * kh + 3]);
      unsigned int u2 = pk2(p[8 * kh + 4], p[8 * kh + 5]);
      unsigned int u3 = pk2(p[8 * kh + 6], p[8 * kh + 7]);
      unsigned int t0 = (unsigned int)__shfl_xor((int)u0, 32);
      unsigned int t1 = (unsigned int)__shfl_xor((int)u1, 32);
      unsigned int t2 = (unsigned int)__shfl_xor((int)u2, 32);
      unsigned int t3 = (unsigned int)__shfl_xor((int)u3, 32);
      unsigned int fr[4];
      fr[0] = hh ? t2 : u0;
      fr[1] = hh ? t3 : u1;
      fr[2] = hh ? u2 : t0;
      fr[3] = hh ? u3 : t1;
      bf16x8 pa = *reinterpret_cast<bf16x8*>(fr);
      __builtin_amdgcn_s_setprio(1);
      pacc0 = __builtin_amdgcn_mfma_f32_32x32x16_bf16(pa, kh ? v01 : v00, pacc0, 0, 0, 0);
      pacc1 = __builtin_amdgcn_mfma_f32_32x32x16_bf16(pa, kh ? v11 : v10, pacc1, 0, 0, 0);
      __builtin_amdgcn_s_setprio(0);
    }
  }

  // ---- cross-j-half reduction via W (wave-private until here) ----
#pragma unroll
  for (int r = 0; r < 16; ++r) {
    int qrow = (r & 3) + 8 * (r >> 2) + 4 * hh;
    Wp[qrow][ql] = pacc0[r];
    Wp[32 + qrow][ql] = pacc1[r];
  }
  float lh = l_acc + __shfl_xor(l_acc, 32);
  if (lane < 32) sl[wv][ql] = lh;
  __syncthreads();

  if (wv < 2) {   // wave wv finalizes q-tile wv: av + linv
    if (lane < 32) {
      float lt = sl[wv][ql] + sl[wv + 2][ql];
      linv[wv * 32 + ql] = 1.0f / lt;
    }
#pragma unroll
    for (int r = 0; r < 16; ++r) {
      int qrow = (r & 3) + 8 * (r >> 2) + 4 * hh;
      float lt = sl[wv][qrow] + sl[wv + 2][qrow];
      float iv = 1.0f / lt;
      float s0v = W[wv][qrow][ql] + W[wv + 2][qrow][ql];
      float s1v = W[wv][32 + qrow][ql] + W[wv + 2][32 + qrow][ql];
      size_t aoff = ((size_t)(q0 + qrow) * NB + b) * DMODEL + h * NDH;
      av_bf[aoff + ql] = f2bf(s0v * iv);
      av_bf[aoff + 32 + ql] = f2bf(s1v * iv);
    }
  }
  __syncthreads();   // linv visible; staging writes drained

  // ---- fused rescale: wave (qtile,jh) normalizes its own staged bf16 ----
  const ushortT* probus = (const ushortT*)prob;
  const int lr = lane >> 4;       // row within stripe (0..3)
  const int cg = lane & 15;       // 16B chunk group
  for (int s = 0; s < 8; ++s) {
    const int rloc = qtile * 32 + s * 4 + lr;
    const int rowg = blockIdx.x * 64 + rloc;
    const size_t ub = ((size_t)bh * TLEN + rowg) * 4096 + 2048 + jh * 1024 + cg * 8;
    const size_t fb = ((size_t)bh * TLEN + rowg) * 2048 + jh * 1024 + cg * 8;
    uint4 a[8];
#pragma unroll
    for (int k = 0; k < 8; ++k)
      a[k] = *reinterpret_cast<const uint4*>(probus + ub + k * 128);
    const float iv = linv[rloc];
    __syncthreads();   // all stripe reads complete before any stripe writes
#pragma unroll
    for (int k = 0; k < 8; ++k) {
      float4 o0, o1;
      o0.x = bf2f((ushortT)(a[k].x & 0xffff)) * iv;
      o0.y = bf2f((ushortT)(a[k].x >> 16)) * iv;
      o0.z = bf2f((ushortT)(a[k].y & 0xffff)) * iv;
      o0.w = bf2f((ushortT)(a[k].y >> 16)) * iv;
      o1.x = bf2f((ushortT)(a[k].z & 0xffff)) * iv;
      o1.y = bf2f((ushortT)(a[k].z >> 16)) * iv;
      o1.z = bf2f((ushortT)(a[k].w & 0xffff)) * iv;
      o1.w = bf2f((ushortT)(a[k].w >> 16)) * iv;
      *reinterpret_cast<float4*>(prob + fb + k * 128) = o0;
      *reinterpret_cast<float4*>(prob + fb + k * 128 + 4) = o1;
    }
  }
}

// ---------------------------------------------------------------------------

extern "C" void kernel_launch(void* const* d_in, const int* in_sizes, int n_in,
                              void* d_out, int out_size, void* d_ws, size_t ws_size,
                              hipStream_t stream) {
  const float* w      = (const float*)d_in[0];   // (T,B,D)
  const float* r      = (const float*)d_in[1];   // (T,D)
  const float* w_qkv  = (const float*)d_in[2];   // (3072,1024)
  const float* w_r    = (const float*)d_in[3];   // (1024,1024)
  const float* w_o    = (const float*)d_in[4];   // (1024,1024)
  const float* bias   = (const float*)d_in[5];   // (16,64)
  const int* mask     = (const int*)d_in[6];     // (T,B) int32

  float* out  = (float*)d_out;
  float* prob = out + (size_t)TLEN * NB * DMODEL;

  const size_t SZ = (size_t)NB * NH * TLEN * NDH;        // 4194304
  ushortT* w_bf    = (ushortT*)d_ws;
  ushortT* wqkv_bf = w_bf + (size_t)4096 * 1024;
  ushortT* r_bf    = wqkv_bf + (size_t)3072 * 1024;
  ushortT* wr_bf   = r_bf + (size_t)2048 * 1024;
  ushortT* wo_bf   = wr_bf + (size_t)1024 * 1024;
  ushortT* q_bf    = wo_bf + (size_t)1024 * 1024;
  ushortT* k_bf    = q_bf + SZ;
  ushortT* vt_bf   = k_bf + SZ;
  ushortT* rk_bf   = vt_bf + SZ;
  ushortT* av_bf   = rk_bf + SZ / 2;
  float* mfl       = (float*)(av_bf + SZ);

  cvt_bf16<<<4096, 256, 0, stream>>>(w, w_bf, 4096 * 1024 / 4);
  cvt_bf16<<<3072, 256, 0, stream>>>(w_qkv, wqkv_bf, 3072 * 1024 / 4);
  cvt_bf16<<<2048, 256, 0, stream>>>(r, r_bf, 2048 * 1024 / 4);
  cvt_bf16<<<1024, 256, 0, stream>>>(w_r, wr_bf, 1024 * 1024 / 4);
  cvt_bf16<<<1024, 256, 0, stream>>>(w_o, wo_bf, 1024 * 1024 / 4);
  cvt_mask<<<8, 256, 0, stream>>>(mask, mfl);

  EpiQKV e1{q_bf, k_bf, vt_bf, bias};
  gemm_bf16<EpiQKV><<<dim3(3072 / 128, 4096 / 128), 256, 0, stream>>>(w_bf, wqkv_bf, DMODEL, e1);
  EpiRK e2{rk_bf};
  gemm_bf16<EpiRK><<<dim3(1024 / 128, 2048 / 128), 256, 0, stream>>>(r_bf, wr_bf, DMODEL, e2);

  attn_mfma<<<dim3(32, 32), 256, 0, stream>>>(q_bf, k_bf, vt_bf, rk_bf,
                                              mfl, prob, av_bf);

  EpiOut e5{out};
  gemm_bf16<EpiOut><<<dim3(1024 / 128, 4096 / 128), 256, 0, stream>>>(av_bf, wo_bf, DMODEL, e5);
}

// Round 8
// 542.776 us; speedup vs baseline: 2.1686x; 1.0869x over previous
//
#include <hip/hip_runtime.h>
#include <hip/hip_bf16.h>
#include <cstdint>
#include <cstddef>

#define TLEN 2048
#define NB 2
#define DMODEL 1024
#define NH 16
#define NDH 64

typedef unsigned short ushortT;
typedef short bf16x8 __attribute__((ext_vector_type(8)));
typedef float f32x16 __attribute__((ext_vector_type(16)));

__device__ __forceinline__ ushortT f2bf(float f) {
  union { float f; unsigned int u; } x{f};
  unsigned int r = x.u + 0x7fff + ((x.u >> 16) & 1);   // RNE
  return (ushortT)(r >> 16);
}
__device__ __forceinline__ unsigned int pk2(float lo, float hi) {
  return ((unsigned int)f2bf(hi) << 16) | (unsigned int)f2bf(lo);
}
__device__ __forceinline__ float bf2f(ushortT u) {
  union { unsigned int u; float f; } x;
  x.u = ((unsigned int)u) << 16;
  return x.f;
}

__device__ __forceinline__ void gld_lds16(const void* g, void* l) {
  __builtin_amdgcn_global_load_lds(
      (const __attribute__((address_space(1))) unsigned int*)g,
      (__attribute__((address_space(3))) unsigned int*)l, 16, 0, 0);
}

// ---------------------------------------------------------------------------
// converts
// ---------------------------------------------------------------------------

__global__ __launch_bounds__(256) void cvt_bf16(const float* __restrict__ in,
                                                ushortT* __restrict__ out, int n4) {
  int i = blockIdx.x * 256 + threadIdx.x;
  if (i < n4) {
    float4 v = reinterpret_cast<const float4*>(in)[i];
    ushort4 o;
    o.x = f2bf(v.x); o.y = f2bf(v.y); o.z = f2bf(v.z); o.w = f2bf(v.w);
    reinterpret_cast<ushort4*>(out)[i] = o;
  }
}

__global__ __launch_bounds__(256) void cvt_mask(const int* __restrict__ mask,
                                                float* __restrict__ mfl) {
  int j = blockIdx.x * 256 + threadIdx.x;
  if (j < TLEN) {
    mfl[j]        = mask[j * NB]     ? 0.f : 1.f;
    mfl[TLEN + j] = mask[j * NB + 1] ? 0.f : 1.f;
  }
}

// ---------------------------------------------------------------------------
// bf16 MFMA GEMM (unchanged)
// ---------------------------------------------------------------------------

template <typename Epi>
__global__ __launch_bounds__(256) void gemm_bf16(const ushortT* __restrict__ A,
                                                 const ushortT* __restrict__ B,
                                                 int K, Epi epi) {
  __shared__ ushortT Al[128 * 64];
  __shared__ ushortT Bl[128 * 64];
  const int tid = threadIdx.x;
  const int lane = tid & 63;
  const int wv = tid >> 6;
  const int wm = wv >> 1, wn = wv & 1;
  const int m0 = blockIdx.y * 128;
  const int n0 = blockIdx.x * 128;
  const int r32 = lane & 31;
  const int hh = lane >> 5;

  f32x16 acc[2][2];
#pragma unroll
  for (int i = 0; i < 2; ++i)
#pragma unroll
    for (int j = 0; j < 2; ++j)
#pragma unroll
      for (int e = 0; e < 16; ++e) acc[i][j][e] = 0.f;

  for (int k0 = 0; k0 < K; k0 += 64) {
#pragma unroll
    for (int it = 0; it < 4; ++it) {
      int idx = it * 256 + tid;          // 1024 chunks of 16B
      int r = idx >> 3, c = idx & 7;
      int gcol = k0 + ((c ^ (r & 7)) << 3);
      gld_lds16(A + (size_t)(m0 + r) * K + gcol, Al + idx * 8);
      gld_lds16(B + (size_t)(n0 + r) * K + gcol, Bl + idx * 8);
    }
    asm volatile("s_waitcnt vmcnt(0)");
    __syncthreads();
#pragma unroll
    for (int kc = 0; kc < 4; ++kc) {
      int lc = kc * 2 + hh;              // logical 16B chunk in row
      bf16x8 af[2], bfr[2];
#pragma unroll
      for (int f = 0; f < 2; ++f) {
        int ar = wm * 64 + f * 32 + r32;
        af[f] = *(const bf16x8*)(Al + ar * 64 + ((lc ^ (ar & 7)) << 3));
        int br = wn * 64 + f * 32 + r32;
        bfr[f] = *(const bf16x8*)(Bl + br * 64 + ((lc ^ (br & 7)) << 3));
      }
#pragma unroll
      for (int i = 0; i < 2; ++i)
#pragma unroll
        for (int j = 0; j < 2; ++j)
          acc[i][j] = __builtin_amdgcn_mfma_f32_32x32x16_bf16(af[i], bfr[j],
                                                              acc[i][j], 0, 0, 0);
    }
    __syncthreads();
  }

#pragma unroll
  for (int i = 0; i < 2; ++i)
#pragma unroll
    for (int j = 0; j < 2; ++j)
#pragma unroll
      for (int rg = 0; rg < 16; ++rg) {
        int m = m0 + wm * 64 + i * 32 + (rg & 3) + 8 * (rg >> 2) + 4 * hh;
        int n = n0 + wn * 64 + j * 32 + r32;
        epi.store(m, n, acc[i][j][rg]);
      }
}

struct EpiQKV {
  ushortT* qb; ushortT* kb; ushortT* vtb; const float* bias;
  __device__ void store(int m, int n, float val) const {
    int t = m >> 1, b = m & 1;
    int which = n >> 10;
    int h = (n >> 6) & (NH - 1);
    int dh = n & (NDH - 1);
    int bh = b * NH + h;
    if (which == 0)
      qb[((size_t)bh * TLEN + t) * NDH + dh] = f2bf(val + bias[(h << 6) | dh]);
    else if (which == 1)
      kb[((size_t)bh * TLEN + t) * NDH + dh] = f2bf(val);
    else
      vtb[((size_t)bh * NDH + dh) * TLEN + t] = f2bf(val);
  }
};

struct EpiRK {
  ushortT* rk;
  __device__ void store(int m, int n, float val) const {
    int h = n >> 6, dh = n & 63;
    rk[((size_t)h * TLEN + m) * NDH + dh] = f2bf(val);
  }
};

struct EpiOut {
  float* out;
  __device__ void store(int m, int n, float val) const {
    out[(size_t)m * DMODEL + n] = val;
  }
};

// ---------------------------------------------------------------------------
// FAST-PATH attention: j-split grid (32,32), 4 waves = (qtile, jhalf).
// Staged p~ goes to a TRANSPOSED buffer S[bh][j/2][q] (uint = bf16 pair
// packed along j): in the MFMA C-layout lanes run along q, so each store is
// 32 consecutive uints = coalesced (16 tx/chunk vs 256 for row-slot stores —
// the measured limiter). av normalized in-block; 1/l written to linv_g for
// the separate transpose-rescale kernel. prob untouched here.
// ---------------------------------------------------------------------------

__global__ __launch_bounds__(256) void attn_fast(
    const ushortT* __restrict__ qb, const ushortT* __restrict__ kb,
    const ushortT* __restrict__ vtb, const ushortT* __restrict__ rkb,
    const float* __restrict__ mfl, unsigned int* __restrict__ S,
    float* __restrict__ linv_g, ushortT* __restrict__ av_bf) {
  __shared__ float W[4][64][32];
  __shared__ float sl[4][32];

  const int bh = blockIdx.y;
  const int b = bh >> 4, h = bh & 15;
  const int wv = threadIdx.x >> 6;
  const int lane = threadIdx.x & 63;
  const int ql = lane & 31;
  const int hh = lane >> 5;
  const int qtile = wv & 1;
  const int jh = wv >> 1;
  const int q0 = blockIdx.x * 64 + qtile * 32;
  const int qg = q0 + ql;

  const ushortT* Qbh = qb + (size_t)bh * TLEN * NDH;
  const ushortT* Kbh = kb + (size_t)bh * TLEN * NDH;
  const ushortT* Vbh = vtb + (size_t)bh * NDH * TLEN;
  const ushortT* Rh  = rkb + (size_t)h * TLEN * NDH;
  const float* mflb  = mfl + (size_t)b * TLEN;
  unsigned int* Sb   = S + (size_t)bh * (TLEN / 2) * TLEN;
  float (*Wp)[32] = W[wv];

  bf16x8 Qf[4], Qs[4];
  {
    int r2 = min(qg + 1, TLEN - 1);
#pragma unroll
    for (int c = 0; c < 4; ++c) {
      Qf[c] = *(const bf16x8*)(Qbh + (size_t)qg * NDH + c * 16 + hh * 8);
      Qs[c] = *(const bf16x8*)(Qbh + (size_t)r2 * NDH + c * 16 + hh * 8);
    }
  }

  f32x16 pacc0, pacc1;
#pragma unroll
  for (int i = 0; i < 16; ++i) { pacc0[i] = 0.f; pacc1[i] = 0.f; }
  float l_acc = 0.f;

  const int jbeg = jh * (TLEN / 2);
  const int jend = jbeg + (TLEN / 2);
  for (int j0 = jbeg; j0 < jend; j0 += 32) {
    const int w1b = 2016 - q0 + j0;
    const int w2b = j0 - q0 - 33;
    const int base0 = (j0 <= q0) ? w1b : w2b;
    const int base1 = ((j0 < q0) ? w1b : w2b) + 32;
    const bool t0w1 = (j0 <= q0);
    const bool t1w1 = (j0 < q0);

    int r0 = max(0, min(base0 + ql, TLEN - 1));
    int r1 = max(0, min(base1 + ql, TLEN - 1));
    const ushortT* s0 = Rh + (size_t)r0 * NDH + hh * 8;
    const ushortT* s1 = Rh + (size_t)r1 * NDH + hh * 8;
    const ushortT* sk = Kbh + (size_t)(j0 + ql) * NDH + hh * 8;
    const ushortT* vrow0 = Vbh + (size_t)ql * TLEN + j0 + 8 * hh;
    const ushortT* vrow1 = Vbh + (size_t)(32 + ql) * TLEN + j0 + 8 * hh;
    bf16x8 rk0[4], rk1[4], kk[4];
#pragma unroll
    for (int c = 0; c < 4; ++c) {
      rk0[c] = *(const bf16x8*)(s0 + c * 16);
      rk1[c] = *(const bf16x8*)(s1 + c * 16);
      kk[c]  = *(const bf16x8*)(sk + c * 16);
    }
    bf16x8 v00 = *(const bf16x8*)(vrow0);
    bf16x8 v01 = *(const bf16x8*)(vrow0 + 16);
    bf16x8 v10 = *(const bf16x8*)(vrow1);
    bf16x8 v11 = *(const bf16x8*)(vrow1 + 16);
    float4 mf4[4];
#pragma unroll
    for (int g = 0; g < 4; ++g)
      mf4[g] = *(const float4*)(mflb + j0 + 8 * g + 4 * hh);

    // BD window tile 0 -> W rows [0,32)
    f32x16 facc;
#pragma unroll
    for (int i = 0; i < 16; ++i) facc[i] = 0.f;
    __builtin_amdgcn_s_setprio(1);
#pragma unroll
    for (int c = 0; c < 4; ++c)
      facc = __builtin_amdgcn_mfma_f32_32x32x16_bf16(rk0[c], t0w1 ? Qf[c] : Qs[c], facc, 0, 0, 0);
    __builtin_amdgcn_s_setprio(0);
#pragma unroll
    for (int r = 0; r < 16; ++r)
      Wp[(r & 3) + 8 * (r >> 2) + 4 * hh][ql] = facc[r];

    // BD window tile 1 -> W rows [32,64)  (reuse facc)
#pragma unroll
    for (int i = 0; i < 16; ++i) facc[i] = 0.f;
    __builtin_amdgcn_s_setprio(1);
#pragma unroll
    for (int c = 0; c < 4; ++c)
      facc = __builtin_amdgcn_mfma_f32_32x32x16_bf16(rk1[c], t1w1 ? Qf[c] : Qs[c], facc, 0, 0, 0);
    __builtin_amdgcn_s_setprio(0);
#pragma unroll
    for (int r = 0; r < 16; ++r)
      Wp[32 + (r & 3) + 8 * (r >> 2) + 4 * hh][ql] = facc[r];

    // AC tile (S^T)
    f32x16 cacc;
#pragma unroll
    for (int i = 0; i < 16; ++i) cacc[i] = 0.f;
    __builtin_amdgcn_s_setprio(1);
#pragma unroll
    for (int c = 0; c < 4; ++c)
      cacc = __builtin_amdgcn_mfma_f32_32x32x16_bf16(kk[c], Qf[c], cacc, 0, 0, 0);
    __builtin_amdgcn_s_setprio(0);

    float p[16];
#pragma unroll
    for (int r = 0; r < 16; ++r) {
      int jrow = (r & 3) + 8 * (r >> 2) + 4 * hh;
      int jg = j0 + jrow;
      float bd = (jg == qg + 1) ? 0.f : Wp[jrow - ql + 31][ql];
      float sc = (cacc[r] + bd) * 0.125f;
      float mv = (&mf4[r >> 2].x)[r & 3];
      float pv = mv * __expf(sc);
      p[r] = pv;
      l_acc += pv;
    }

    // packed bf16 j-pairs, shared by S stores and PV A-frags
    unsigned int u[8];
#pragma unroll
    for (int i = 0; i < 8; ++i) u[i] = pk2(p[2 * i], p[2 * i + 1]);

    // coalesced transposed staging: S[bh][(j0+jrow)/2][qg]
#pragma unroll
    for (int i = 0; i < 8; ++i) {
      int r = 2 * i;
      int jrow = (r & 3) + 8 * (r >> 2) + 4 * hh;   // even
      Sb[(size_t)((j0 + jrow) >> 1) * TLEN + qg] = u[i];
    }

#pragma unroll
    for (int kh = 0; kh < 2; ++kh) {
      unsigned int t0 = (unsigned int)__shfl_xor((int)u[4 * kh + 0], 32);
      unsigned int t1 = (unsigned int)__shfl_xor((int)u[4 * kh + 1], 32);
      unsigned int t2 = (unsigned int)__shfl_xor((int)u[4 * kh + 2], 32);
      unsigned int t3 = (unsigned int)__shfl_xor((int)u[4 * kh + 3], 32);
      unsigned int fr[4];
      fr[0] = hh ? t2 : u[4 * kh + 0];
      fr[1] = hh ? t3 : u[4 * kh + 1];
      fr[2] = hh ? u[4 * kh + 2] : t0;
      fr[3] = hh ? u[4 * kh + 3] : t1;
      bf16x8 pa = *reinterpret_cast<bf16x8*>(fr);
      __builtin_amdgcn_s_setprio(1);
      pacc0 = __builtin_amdgcn_mfma_f32_32x32x16_bf16(pa, kh ? v01 : v00, pacc0, 0, 0, 0);
      pacc1 = __builtin_amdgcn_mfma_f32_32x32x16_bf16(pa, kh ? v11 : v10, pacc1, 0, 0, 0);
      __builtin_amdgcn_s_setprio(0);
    }
  }

  // ---- cross-j-half reduction via W ----
#pragma unroll
  for (int r = 0; r < 16; ++r) {
    int qrow = (r & 3) + 8 * (r >> 2) + 4 * hh;
    Wp[qrow][ql] = pacc0[r];
    Wp[32 + qrow][ql] = pacc1[r];
  }
  float lh = l_acc + __shfl_xor(l_acc, 32);
  if (lane < 32) sl[wv][ql] = lh;
  __syncthreads();

  if (wv < 2) {   // wave wv finalizes q-tile wv: av + 1/l
    if (lane < 32) {
      float lt = sl[wv][ql] + sl[wv + 2][ql];
      linv_g[(size_t)bh * TLEN + q0 + ql] = 1.0f / lt;
    }
#pragma unroll
    for (int r = 0; r < 16; ++r) {
      int qrow = (r & 3) + 8 * (r >> 2) + 4 * hh;
      float lt = sl[wv][qrow] + sl[wv + 2][qrow];
      float iv = 1.0f / lt;
      float s0v = W[wv][qrow][ql] + W[wv + 2][qrow][ql];
      float s1v = W[wv][32 + qrow][ql] + W[wv + 2][32 + qrow][ql];
      size_t aoff = ((size_t)(q0 + qrow) * NB + b) * DMODEL + h * NDH;
      av_bf[aoff + ql] = f2bf(s0v * iv);
      av_bf[aoff + 32 + ql] = f2bf(s1v * iv);
    }
  }
}

// ---------------------------------------------------------------------------
// Transpose-rescale: S[bh][jp][q] (bf16 j-pairs) -> prob[bh][q][j] f32 * 1/l.
// 64jp x 64q tile through LDS; fully coalesced reads and writes.
// ---------------------------------------------------------------------------

__global__ __launch_bounds__(256) void rescale_t(const unsigned int* __restrict__ S,
                                                 const float* __restrict__ linv_g,
                                                 float* __restrict__ prob) {
  __shared__ unsigned int lds[64][65];
  __shared__ float liv[64];
  const int qt = blockIdx.x;   // 32 tiles of 64 q
  const int jt = blockIdx.y;   // 16 tiles of 64 jp (=128 j)
  const int bh = blockIdx.z;
  const int t = threadIdx.x;

  const unsigned int* Sb = S + ((size_t)bh * (TLEN / 2) + jt * 64) * TLEN + qt * 64;
  {
    int row = t >> 2, c0 = (t & 3) * 16;
#pragma unroll
    for (int k = 0; k < 4; ++k) {
      uint4 v = *reinterpret_cast<const uint4*>(Sb + (size_t)row * TLEN + c0 + k * 4);
      lds[row][c0 + k * 4 + 0] = v.x;
      lds[row][c0 + k * 4 + 1] = v.y;
      lds[row][c0 + k * 4 + 2] = v.z;
      lds[row][c0 + k * 4 + 3] = v.w;
    }
  }
  if (t < 64) liv[t] = linv_g[(size_t)bh * TLEN + qt * 64 + t];
  __syncthreads();

  float* P = prob + ((size_t)bh * TLEN + qt * 64) * TLEN + jt * 128;
#pragma unroll
  for (int k = 0; k < 8; ++k) {
    int idx = k * 256 + t;             // 2048 float4 = 64 rows x 32
    int row = idx >> 5, c4 = idx & 31;
    unsigned int u0 = lds[c4 * 2][row];
    unsigned int u1 = lds[c4 * 2 + 1][row];
    float iv = liv[row];
    float4 o;
    o.x = bf2f((ushortT)(u0 & 0xffff)) * iv;
    o.y = bf2f((ushortT)(u0 >> 16)) * iv;
    o.z = bf2f((ushortT)(u1 & 0xffff)) * iv;
    o.w = bf2f((ushortT)(u1 >> 16)) * iv;
    *reinterpret_cast<float4*>(P + (size_t)row * TLEN + c4 * 4) = o;
  }
}

// ---------------------------------------------------------------------------
// FALLBACK attention (exact R7 kernel): fused rescale, staging inside prob.
// Used only if d_ws is too small for the transposed staging buffer.
// ---------------------------------------------------------------------------

__global__ __launch_bounds__(256) void attn_fused(
    const ushortT* __restrict__ qb, const ushortT* __restrict__ kb,
    const ushortT* __restrict__ vtb, const ushortT* __restrict__ rkb,
    const float* __restrict__ mfl, float* __restrict__ prob,
    ushortT* __restrict__ av_bf) {
  __shared__ float W[4][64][32];
  __shared__ float sl[4][32];
  __shared__ float linv[64];

  const int bh = blockIdx.y;
  const int b = bh >> 4, h = bh & 15;
  const int wv = threadIdx.x >> 6;
  const int lane = threadIdx.x & 63;
  const int ql = lane & 31;
  const int hh = lane >> 5;
  const int qtile = wv & 1;
  const int jh = wv >> 1;
  const int q0 = blockIdx.x * 64 + qtile * 32;
  const int qg = q0 + ql;

  const ushortT* Qbh = qb + (size_t)bh * TLEN * NDH;
  const ushortT* Kbh = kb + (size_t)bh * TLEN * NDH;
  const ushortT* Vbh = vtb + (size_t)bh * NDH * TLEN;
  const ushortT* Rh  = rkb + (size_t)h * TLEN * NDH;
  const float* mflb  = mfl + (size_t)b * TLEN;
  float (*Wp)[32] = W[wv];

  bf16x8 Qf[4], Qs[4];
  {
    int r2 = min(qg + 1, TLEN - 1);
#pragma unroll
    for (int c = 0; c < 4; ++c) {
      Qf[c] = *(const bf16x8*)(Qbh + (size_t)qg * NDH + c * 16 + hh * 8);
      Qs[c] = *(const bf16x8*)(Qbh + (size_t)r2 * NDH + c * 16 + hh * 8);
    }
  }

  f32x16 pacc0, pacc1;
#pragma unroll
  for (int i = 0; i < 16; ++i) { pacc0[i] = 0.f; pacc1[i] = 0.f; }
  float l_acc = 0.f;

  ushortT* pbrow = (ushortT*)prob + ((size_t)bh * TLEN + qg) * 4096 + 2048;

  const int jbeg = jh * (TLEN / 2);
  const int jend = jbeg + (TLEN / 2);
  for (int j0 = jbeg; j0 < jend; j0 += 32) {
    const int w1b = 2016 - q0 + j0;
    const int w2b = j0 - q0 - 33;
    const int base0 = (j0 <= q0) ? w1b : w2b;
    const int base1 = ((j0 < q0) ? w1b : w2b) + 32;
    const bool t0w1 = (j0 <= q0);
    const bool t1w1 = (j0 < q0);

    int r0 = max(0, min(base0 + ql, TLEN - 1));
    int r1 = max(0, min(base1 + ql, TLEN - 1));
    const ushortT* s0 = Rh + (size_t)r0 * NDH + hh * 8;
    const ushortT* s1 = Rh + (size_t)r1 * NDH + hh * 8;
    const ushortT* sk = Kbh + (size_t)(j0 + ql) * NDH + hh * 8;
    const ushortT* vrow0 = Vbh + (size_t)ql * TLEN + j0 + 8 * hh;
    const ushortT* vrow1 = Vbh + (size_t)(32 + ql) * TLEN + j0 + 8 * hh;
    bf16x8 rk0[4], rk1[4], kk[4];
#pragma unroll
    for (int c = 0; c < 4; ++c) {
      rk0[c] = *(const bf16x8*)(s0 + c * 16);
      rk1[c] = *(const bf16x8*)(s1 + c * 16);
      kk[c]  = *(const bf16x8*)(sk + c * 16);
    }
    bf16x8 v00 = *(const bf16x8*)(vrow0);
    bf16x8 v01 = *(const bf16x8*)(vrow0 + 16);
    bf16x8 v10 = *(const bf16x8*)(vrow1);
    bf16x8 v11 = *(const bf16x8*)(vrow1 + 16);
    float4 mf4[4];
#pragma unroll
    for (int g = 0; g < 4; ++g)
      mf4[g] = *(const float4*)(mflb + j0 + 8 * g + 4 * hh);

    f32x16 facc;
#pragma unroll
    for (int i = 0; i < 16; ++i) facc[i] = 0.f;
    __builtin_amdgcn_s_setprio(1);
#pragma unroll
    for (int c = 0; c < 4; ++c)
      facc = __builtin_amdgcn_mfma_f32_32x32x16_bf16(rk0[c], t0w1 ? Qf[c] : Qs[c], facc, 0, 0, 0);
    __builtin_amdgcn_s_setprio(0);
#pragma unroll
    for (int r = 0; r < 16; ++r)
      Wp[(r & 3) + 8 * (r >> 2) + 4 * hh][ql] = facc[r];

#pragma unroll
    for (int i = 0; i < 16; ++i) facc[i] = 0.f;
    __builtin_amdgcn_s_setprio(1);
#pragma unroll
    for (int c = 0; c < 4; ++c)
      facc = __builtin_amdgcn_mfma_f32_32x32x16_bf16(rk1[c], t1w1 ? Qf[c] : Qs[c], facc, 0, 0, 0);
    __builtin_amdgcn_s_setprio(0);
#pragma unroll
    for (int r = 0; r < 16; ++r)
      Wp[32 + (r & 3) + 8 * (r >> 2) + 4 * hh][ql] = facc[r];

    f32x16 cacc;
#pragma unroll
    for (int i = 0; i < 16; ++i) cacc[i] = 0.f;
    __builtin_amdgcn_s_setprio(1);
#pragma unroll
    for (int c = 0; c < 4; ++c)
      cacc = __builtin_amdgcn_mfma_f32_32x32x16_bf16(kk[c], Qf[c], cacc, 0, 0, 0);
    __builtin_amdgcn_s_setprio(0);

    float p[16];
#pragma unroll
    for (int r = 0; r < 16; ++r) {
      int jrow = (r & 3) + 8 * (r >> 2) + 4 * hh;
      int jg = j0 + jrow;
      float bd = (jg == qg + 1) ? 0.f : Wp[jrow - ql + 31][ql];
      float sc = (cacc[r] + bd) * 0.125f;
      float mv = (&mf4[r >> 2].x)[r & 3];
      float pv = mv * __expf(sc);
      p[r] = pv;
      l_acc += pv;
    }

#pragma unroll
    for (int g = 0; g < 4; ++g) {
      uint2 st;
      st.x = pk2(p[4 * g + 0], p[4 * g + 1]);
      st.y = pk2(p[4 * g + 2], p[4 * g + 3]);
      *reinterpret_cast<uint2*>(pbrow + j0 + 8 * g + 4 * hh) = st;
    }

#pragma unroll
    for (int kh = 0; kh < 2; ++kh) {
      unsigned int u0 = pk2(p[8 * kh + 0], p[8 * kh + 1]);
      unsigned int u1 = pk2(p[8 * kh + 2], p[8 * kh + 3]);
      unsigned int u2 = pk2(p[8 * kh + 4], p[8 * kh + 5]);
      unsigned int u3 = pk2(p[8 * kh + 6], p[8 * kh + 7]);
      unsigned int t0 = (unsigned int)__shfl_xor((int)u0, 32);
      unsigned int t1 = (unsigned int)__shfl_xor((int)u1, 32);
      unsigned int t2 = (unsigned int)__shfl_xor((int)u2, 32);
      unsigned int t3 = (unsigned int)__shfl_xor((int)u3, 32);
      unsigned int fr[4];
      fr[0] = hh ? t2 : u0;
      fr[1] = hh ? t3 : u1;
      fr[2] = hh ? u2 : t0;
      fr[3] = hh ? u3 : t1;
      bf16x8 pa = *reinterpret_cast<bf16x8*>(fr);
      __builtin_amdgcn_s_setprio(1);
      pacc0 = __builtin_amdgcn_mfma_f32_32x32x16_bf16(pa, kh ? v01 : v00, pacc0, 0, 0, 0);
      pacc1 = __builtin_amdgcn_mfma_f32_32x32x16_bf16(pa, kh ? v11 : v10, pacc1, 0, 0, 0);
      __builtin_amdgcn_s_setprio(0);
    }
  }

#pragma unroll
  for (int r = 0; r < 16; ++r) {
    int qrow = (r & 3) + 8 * (r >> 2) + 4 * hh;
    Wp[qrow][ql] = pacc0[r];
    Wp[32 + qrow][ql] = pacc1[r];
  }
  float lh = l_acc + __shfl_xor(l_acc, 32);
  if (lane < 32) sl[wv][ql] = lh;
  __syncthreads();

  if (wv < 2) {
    if (lane < 32) {
      float lt = sl[wv][ql] + sl[wv + 2][ql];
      linv[wv * 32 + ql] = 1.0f / lt;
    }
#pragma unroll
    for (int r = 0; r < 16; ++r) {
      int qrow = (r & 3) + 8 * (r >> 2) + 4 * hh;
      float lt = sl[wv][qrow] + sl[wv + 2][qrow];
      float iv = 1.0f / lt;
      float s0v = W[wv][qrow][ql] + W[wv + 2][qrow][ql];
      float s1v = W[wv][32 + qrow][ql] + W[wv + 2][32 + qrow][ql];
      size_t aoff = ((size_t)(q0 + qrow) * NB + b) * DMODEL + h * NDH;
      av_bf[aoff + ql] = f2bf(s0v * iv);
      av_bf[aoff + 32 + ql] = f2bf(s1v * iv);
    }
  }
  __syncthreads();

  const ushortT* probus = (const ushortT*)prob;
  const int lr = lane >> 4;
  const int cg = lane & 15;
  for (int s = 0; s < 8; ++s) {
    const int rloc = qtile * 32 + s * 4 + lr;
    const int rowg = blockIdx.x * 64 + rloc;
    const size_t ub = ((size_t)bh * TLEN + rowg) * 4096 + 2048 + jh * 1024 + cg * 8;
    const size_t fb = ((size_t)bh * TLEN + rowg) * 2048 + jh * 1024 + cg * 8;
    uint4 a[8];
#pragma unroll
    for (int k = 0; k < 8; ++k)
      a[k] = *reinterpret_cast<const uint4*>(probus + ub + k * 128);
    const float iv = linv[rloc];
    __syncthreads();
#pragma unroll
    for (int k = 0; k < 8; ++k) {
      float4 o0, o1;
      o0.x = bf2f((ushortT)(a[k].x & 0xffff)) * iv;
      o0.y = bf2f((ushortT)(a[k].x >> 16)) * iv;
      o0.z = bf2f((ushortT)(a[k].y & 0xffff)) * iv;
      o0.w = bf2f((ushortT)(a[k].y >> 16)) * iv;
      o1.x = bf2f((ushortT)(a[k].z & 0xffff)) * iv;
      o1.y = bf2f((ushortT)(a[k].z >> 16)) * iv;
      o1.z = bf2f((ushortT)(a[k].w & 0xffff)) * iv;
      o1.w = bf2f((ushortT)(a[k].w >> 16)) * iv;
      *reinterpret_cast<float4*>(prob + fb + k * 128) = o0;
      *reinterpret_cast<float4*>(prob + fb + k * 128 + 4) = o1;
    }
  }
}

// ---------------------------------------------------------------------------

extern "C" void kernel_launch(void* const* d_in, const int* in_sizes, int n_in,
                              void* d_out, int out_size, void* d_ws, size_t ws_size,
                              hipStream_t stream) {
  const float* w      = (const float*)d_in[0];   // (T,B,D)
  const float* r      = (const float*)d_in[1];   // (T,D)
  const float* w_qkv  = (const float*)d_in[2];   // (3072,1024)
  const float* w_r    = (const float*)d_in[3];   // (1024,1024)
  const float* w_o    = (const float*)d_in[4];   // (1024,1024)
  const float* bias   = (const float*)d_in[5];   // (16,64)
  const int* mask     = (const int*)d_in[6];     // (T,B) int32

  float* out  = (float*)d_out;
  float* prob = out + (size_t)TLEN * NB * DMODEL;

  const size_t SZ = (size_t)NB * NH * TLEN * NDH;        // 4194304
  ushortT* w_bf    = (ushortT*)d_ws;
  ushortT* wqkv_bf = w_bf + (size_t)4096 * 1024;
  ushortT* r_bf    = wqkv_bf + (size_t)3072 * 1024;
  ushortT* wr_bf   = r_bf + (size_t)2048 * 1024;
  ushortT* wo_bf   = wr_bf + (size_t)1024 * 1024;
  ushortT* q_bf    = wo_bf + (size_t)1024 * 1024;
  ushortT* k_bf    = q_bf + SZ;
  ushortT* vt_bf   = k_bf + SZ;
  ushortT* rk_bf   = vt_bf + SZ;
  ushortT* av_bf   = rk_bf + SZ / 2;
  float* mfl       = (float*)(av_bf + SZ);
  float* linv_g    = mfl + (size_t)NB * TLEN;
  unsigned int* S  = (unsigned int*)(linv_g + (size_t)NB * NH * TLEN);
  const size_t need = (size_t)((char*)(S + (size_t)NB * NH * (TLEN / 2) * TLEN) -
                               (char*)d_ws);
  const bool fast = ws_size >= need;

  cvt_bf16<<<4096, 256, 0, stream>>>(w, w_bf, 4096 * 1024 / 4);
  cvt_bf16<<<3072, 256, 0, stream>>>(w_qkv, wqkv_bf, 3072 * 1024 / 4);
  cvt_bf16<<<2048, 256, 0, stream>>>(r, r_bf, 2048 * 1024 / 4);
  cvt_bf16<<<1024, 256, 0, stream>>>(w_r, wr_bf, 1024 * 1024 / 4);
  cvt_bf16<<<1024, 256, 0, stream>>>(w_o, wo_bf, 1024 * 1024 / 4);
  cvt_mask<<<8, 256, 0, stream>>>(mask, mfl);

  EpiQKV e1{q_bf, k_bf, vt_bf, bias};
  gemm_bf16<EpiQKV><<<dim3(3072 / 128, 4096 / 128), 256, 0, stream>>>(w_bf, wqkv_bf, DMODEL, e1);
  EpiRK e2{rk_bf};
  gemm_bf16<EpiRK><<<dim3(1024 / 128, 2048 / 128), 256, 0, stream>>>(r_bf, wr_bf, DMODEL, e2);

  if (fast) {
    attn_fast<<<dim3(32, 32), 256, 0, stream>>>(q_bf, k_bf, vt_bf, rk_bf,
                                                mfl, S, linv_g, av_bf);
    rescale_t<<<dim3(32, 16, 32), 256, 0, stream>>>(S, linv_g, prob);
  } else {
    attn_fused<<<dim3(32, 32), 256, 0, stream>>>(q_bf, k_bf, vt_bf, rk_bf,
                                                 mfl, prob, av_bf);
  }

  EpiOut e5{out};
  gemm_bf16<EpiOut><<<dim3(1024 / 128, 4096 / 128), 256, 0, stream>>>(av_bf, wo_bf, DMODEL, e5);
}

// Round 9
// 471.299 us; speedup vs baseline: 2.4974x; 1.1517x over previous
//
#include <hip/hip_runtime.h>
#include <hip/hip_bf16.h>
#include <cstdint>
#include <cstddef>

#define TLEN 2048
#define NB 2
#define DMODEL 1024
#define NH 16
#define NDH 64

typedef unsigned short ushortT;
typedef short bf16x8 __attribute__((ext_vector_type(8)));
typedef float f32x16 __attribute__((ext_vector_type(16)));

__device__ __forceinline__ ushortT f2bf(float f) {
  union { float f; unsigned int u; } x{f};
  unsigned int r = x.u + 0x7fff + ((x.u >> 16) & 1);   // RNE
  return (ushortT)(r >> 16);
}
__device__ __forceinline__ unsigned int pk2(float lo, float hi) {
  return ((unsigned int)f2bf(hi) << 16) | (unsigned int)f2bf(lo);
}
__device__ __forceinline__ float bf2f(ushortT u) {
  union { unsigned int u; float f; } x;
  x.u = ((unsigned int)u) << 16;
  return x.f;
}

__device__ __forceinline__ void gld_lds16(const void* g, void* l) {
  __builtin_amdgcn_global_load_lds(
      (const __attribute__((address_space(1))) unsigned int*)g,
      (__attribute__((address_space(3))) unsigned int*)l, 16, 0, 0);
}

// ---------------------------------------------------------------------------
// converts
// ---------------------------------------------------------------------------

__global__ __launch_bounds__(256) void cvt_bf16(const float* __restrict__ in,
                                                ushortT* __restrict__ out, int n4) {
  int i = blockIdx.x * 256 + threadIdx.x;
  if (i < n4) {
    float4 v = reinterpret_cast<const float4*>(in)[i];
    ushort4 o;
    o.x = f2bf(v.x); o.y = f2bf(v.y); o.z = f2bf(v.z); o.w = f2bf(v.w);
    reinterpret_cast<ushort4*>(out)[i] = o;
  }
}

__global__ __launch_bounds__(256) void cvt_mask(const int* __restrict__ mask,
                                                float* __restrict__ mfl) {
  int j = blockIdx.x * 256 + threadIdx.x;
  if (j < TLEN) {
    mfl[j]        = mask[j * NB]     ? 0.f : 1.f;
    mfl[TLEN + j] = mask[j * NB + 1] ? 0.f : 1.f;
  }
}

// zero row 2048 of rk_ext for each head (ws is poisoned, not zeroed)
__global__ __launch_bounds__(256) void zero_rkext(ushortT* __restrict__ rkE) {
  int i = threadIdx.x;          // 256 threads x 4 ushorts = 16 heads x 64
  int h = i >> 4, c = i & 15;
  ushort4 z; z.x = 0; z.y = 0; z.z = 0; z.w = 0;
  *reinterpret_cast<ushort4*>(rkE + ((size_t)h * 4096 + 2048) * NDH + c * 4) = z;
}

// ---------------------------------------------------------------------------
// bf16 MFMA GEMM (unchanged)
// ---------------------------------------------------------------------------

template <typename Epi>
__global__ __launch_bounds__(256) void gemm_bf16(const ushortT* __restrict__ A,
                                                 const ushortT* __restrict__ B,
                                                 int K, Epi epi) {
  __shared__ ushortT Al[128 * 64];
  __shared__ ushortT Bl[128 * 64];
  const int tid = threadIdx.x;
  const int lane = tid & 63;
  const int wv = tid >> 6;
  const int wm = wv >> 1, wn = wv & 1;
  const int m0 = blockIdx.y * 128;
  const int n0 = blockIdx.x * 128;
  const int r32 = lane & 31;
  const int hh = lane >> 5;

  f32x16 acc[2][2];
#pragma unroll
  for (int i = 0; i < 2; ++i)
#pragma unroll
    for (int j = 0; j < 2; ++j)
#pragma unroll
      for (int e = 0; e < 16; ++e) acc[i][j][e] = 0.f;

  for (int k0 = 0; k0 < K; k0 += 64) {
#pragma unroll
    for (int it = 0; it < 4; ++it) {
      int idx = it * 256 + tid;          // 1024 chunks of 16B
      int r = idx >> 3, c = idx & 7;
      int gcol = k0 + ((c ^ (r & 7)) << 3);
      gld_lds16(A + (size_t)(m0 + r) * K + gcol, Al + idx * 8);
      gld_lds16(B + (size_t)(n0 + r) * K + gcol, Bl + idx * 8);
    }
    asm volatile("s_waitcnt vmcnt(0)");
    __syncthreads();
#pragma unroll
    for (int kc = 0; kc < 4; ++kc) {
      int lc = kc * 2 + hh;              // logical 16B chunk in row
      bf16x8 af[2], bfr[2];
#pragma unroll
      for (int f = 0; f < 2; ++f) {
        int ar = wm * 64 + f * 32 + r32;
        af[f] = *(const bf16x8*)(Al + ar * 64 + ((lc ^ (ar & 7)) << 3));
        int br = wn * 64 + f * 32 + r32;
        bfr[f] = *(const bf16x8*)(Bl + br * 64 + ((lc ^ (br & 7)) << 3));
      }
#pragma unroll
      for (int i = 0; i < 2; ++i)
#pragma unroll
        for (int j = 0; j < 2; ++j)
          acc[i][j] = __builtin_amdgcn_mfma_f32_32x32x16_bf16(af[i], bfr[j],
                                                              acc[i][j], 0, 0, 0);
    }
    __syncthreads();
  }

#pragma unroll
  for (int i = 0; i < 2; ++i)
#pragma unroll
    for (int j = 0; j < 2; ++j)
#pragma unroll
      for (int rg = 0; rg < 16; ++rg) {
        int m = m0 + wm * 64 + i * 32 + (rg & 3) + 8 * (rg >> 2) + 4 * hh;
        int n = n0 + wn * 64 + j * 32 + r32;
        epi.store(m, n, acc[i][j][rg]);
      }
}

struct EpiQKV {
  ushortT* qb; ushortT* kb; ushortT* vtb; const float* bias;
  __device__ void store(int m, int n, float val) const {
    int t = m >> 1, b = m & 1;
    int which = n >> 10;
    int h = (n >> 6) & (NH - 1);
    int dh = n & (NDH - 1);
    int bh = b * NH + h;
    if (which == 0)
      qb[((size_t)bh * TLEN + t) * NDH + dh] = f2bf(val + bias[(h << 6) | dh]);
    else if (which == 1)
      kb[((size_t)bh * TLEN + t) * NDH + dh] = f2bf(val);
    else
      vtb[((size_t)bh * NDH + dh) * TLEN + t] = f2bf(val);
  }
};

struct EpiRK {   // rk_ext: row m = rk[m] (m<=2047); row 2048 = 0 (separate
                 // kernel); row m = rk[m-2049] (m>=2049)
  ushortT* rkE;
  __device__ void store(int m, int n, float val) const {
    int h = n >> 6, dh = n & 63;
    ushortT v = f2bf(val);
    rkE[((size_t)h * 4096 + m) * NDH + dh] = v;
    if (m <= 2046)
      rkE[((size_t)h * 4096 + m + 2049) * NDH + dh] = v;
  }
};

struct EpiOut {
  float* out;
  __device__ void store(int m, int n, float val) const {
    out[(size_t)m * DMODEL + n] = val;
  }
};

// ---------------------------------------------------------------------------
// FAST attention, LDS-staged. Grid (32,32): blockIdx.y = bh, blockIdx.x = 64
// q rows. Block = 2 waves (one per 32-q tile), both covering all j.
// Per 32-j chunk the block cooperatively stages (global_load_lds, source-side
// XOR swizzle):
//   KT: K[j0..j0+32)[64d]                  4KB
//   VT: Vt[64d][j0..j0+32)                 4KB
//   RK: rk_ext rows [U, U+96), U=1984+j0-Q0  12KB  (union of both q-tiles'
//       64-row windows; wave t reads LDS rows 32(1-t)+[0,64))
// BD row for element (q,j) = rk_ext[2047+j-q]; the j==q+1 zero comes from
// rk_ext row 2048 = 0; Qf/Qs selection stays chunk-level (t0w1/t1w1).
// p~ bf16 j-pairs -> transposed S[bh][j/2][q] (coalesced); PV via MFMA.
// ---------------------------------------------------------------------------

__global__ __launch_bounds__(128) void attn_fast(
    const ushortT* __restrict__ qb, const ushortT* __restrict__ kb,
    const ushortT* __restrict__ vtb, const ushortT* __restrict__ rkE,
    const float* __restrict__ mfl, unsigned int* __restrict__ S,
    float* __restrict__ linv_g, ushortT* __restrict__ av_bf) {
  __shared__ float W[2][64][32];
  __shared__ ushortT KT[2048];   // [32 j][8 x 16B chunks], chunk c at c^(row&7)
  __shared__ ushortT VT[2048];   // [64 d][4 x 16B chunks], chunk c at c^(d&3)
  __shared__ ushortT RK[6144];   // [96 rows][8 chunks],    chunk c at c^(row&7)

  const int bh = blockIdx.y;
  const int b = bh >> 4, h = bh & 15;
  const int t = threadIdx.x >> 6;        // q-tile wave
  const int lane = threadIdx.x & 63;
  const int ql = lane & 31;
  const int hh = lane >> 5;
  const int Q0 = blockIdx.x * 64;
  const int q0 = Q0 + 32 * t;
  const int qg = q0 + ql;

  const ushortT* Qbh = qb + (size_t)bh * TLEN * NDH;
  const ushortT* Kbh = kb + (size_t)bh * TLEN * NDH;
  const ushortT* Vbh = vtb + (size_t)bh * NDH * TLEN;
  const ushortT* Rh  = rkE + (size_t)h * 4096 * NDH;
  const float* mflb  = mfl + (size_t)b * TLEN;
  unsigned int* Sb   = S + (size_t)bh * (TLEN / 2) * TLEN;
  float (*Wp)[32] = W[t];

  bf16x8 Qf[4], Qs[4];
  {
    int r2 = min(qg + 1, TLEN - 1);
#pragma unroll
    for (int c = 0; c < 4; ++c) {
      Qf[c] = *(const bf16x8*)(Qbh + (size_t)qg * NDH + c * 16 + hh * 8);
      Qs[c] = *(const bf16x8*)(Qbh + (size_t)r2 * NDH + c * 16 + hh * 8);
    }
  }

  f32x16 pacc0, pacc1;
#pragma unroll
  for (int i = 0; i < 16; ++i) { pacc0[i] = 0.f; pacc1[i] = 0.f; }
  float l_acc = 0.f;

  for (int j0 = 0; j0 < TLEN; j0 += 32) {
    __syncthreads();                       // tiles free to overwrite
    const int U = 1984 + j0 - Q0;          // in [0, 4000]; U+96 <= 4096
#pragma unroll
    for (int i = 0; i < 6; ++i) {          // RK: 12 insts over 2 waves
      int ci = (t * 6 + i) * 64 + lane;
      int row = ci >> 3, c = ci & 7;
      gld_lds16(Rh + (size_t)(U + row) * NDH + ((c ^ (row & 7)) << 3), RK + ci * 8);
    }
#pragma unroll
    for (int i = 0; i < 2; ++i) {          // KT + VT: 4+4 insts over 2 waves
      int ci = (t * 2 + i) * 64 + lane;
      int row = ci >> 3, c = ci & 7;
      gld_lds16(Kbh + (size_t)(j0 + row) * NDH + ((c ^ (row & 7)) << 3), KT + ci * 8);
      int d = ci >> 2, c2 = ci & 3;
      gld_lds16(Vbh + (size_t)d * TLEN + j0 + ((c2 ^ (d & 3)) << 3), VT + ci * 8);
    }
    float4 mf4[4];
#pragma unroll
    for (int g = 0; g < 4; ++g)
      mf4[g] = *(const float4*)(mflb + j0 + 8 * g + 4 * hh);
    asm volatile("s_waitcnt vmcnt(0)");
    __syncthreads();                       // tiles visible

    const bool t0w1 = (j0 <= q0);
    const bool t1w1 = (j0 < q0);
    const int R1 = 32 * (1 - t) + ql;      // LDS row of rk window, tile 1
    const int R2 = R1 + 32;

    // BD tile 1 -> W rows [0,32)
    f32x16 facc;
#pragma unroll
    for (int i = 0; i < 16; ++i) facc[i] = 0.f;
    __builtin_amdgcn_s_setprio(1);
#pragma unroll
    for (int c = 0; c < 4; ++c) {
      bf16x8 a = *(const bf16x8*)(RK + R1 * NDH + (((2 * c + hh) ^ (R1 & 7)) << 3));
      facc = __builtin_amdgcn_mfma_f32_32x32x16_bf16(a, t0w1 ? Qf[c] : Qs[c], facc, 0, 0, 0);
    }
    __builtin_amdgcn_s_setprio(0);
#pragma unroll
    for (int r = 0; r < 16; ++r)
      Wp[(r & 3) + 8 * (r >> 2) + 4 * hh][ql] = facc[r];

    // BD tile 2 -> W rows [32,64)
#pragma unroll
    for (int i = 0; i < 16; ++i) facc[i] = 0.f;
    __builtin_amdgcn_s_setprio(1);
#pragma unroll
    for (int c = 0; c < 4; ++c) {
      bf16x8 a = *(const bf16x8*)(RK + R2 * NDH + (((2 * c + hh) ^ (R2 & 7)) << 3));
      facc = __builtin_amdgcn_mfma_f32_32x32x16_bf16(a, t1w1 ? Qf[c] : Qs[c], facc, 0, 0, 0);
    }
    __builtin_amdgcn_s_setprio(0);
#pragma unroll
    for (int r = 0; r < 16; ++r)
      Wp[32 + (r & 3) + 8 * (r >> 2) + 4 * hh][ql] = facc[r];

    // AC tile (S^T)
    f32x16 cacc;
#pragma unroll
    for (int i = 0; i < 16; ++i) cacc[i] = 0.f;
    __builtin_amdgcn_s_setprio(1);
#pragma unroll
    for (int c = 0; c < 4; ++c) {
      bf16x8 a = *(const bf16x8*)(KT + ql * NDH + (((2 * c + hh) ^ (ql & 7)) << 3));
      cacc = __builtin_amdgcn_mfma_f32_32x32x16_bf16(a, Qf[c], cacc, 0, 0, 0);
    }
    __builtin_amdgcn_s_setprio(0);

    float p[16];
#pragma unroll
    for (int r = 0; r < 16; ++r) {
      int jrow = (r & 3) + 8 * (r >> 2) + 4 * hh;
      float bd = Wp[jrow - ql + 31][ql];
      float sc = (cacc[r] + bd) * 0.125f;
      float mv = (&mf4[r >> 2].x)[r & 3];
      float pv = mv * __expf(sc);
      p[r] = pv;
      l_acc += pv;
    }

    unsigned int u[8];
#pragma unroll
    for (int i = 0; i < 8; ++i) u[i] = pk2(p[2 * i], p[2 * i + 1]);

    // coalesced transposed staging: S[bh][(j0+jrow)/2][qg]
#pragma unroll
    for (int i = 0; i < 8; ++i) {
      int r = 2 * i;
      int jrow = (r & 3) + 8 * (r >> 2) + 4 * hh;   // even
      Sb[(size_t)((j0 + jrow) >> 1) * TLEN + qg] = u[i];
    }

#pragma unroll
    for (int kh = 0; kh < 2; ++kh) {
      unsigned int t0 = (unsigned int)__shfl_xor((int)u[4 * kh + 0], 32);
      unsigned int t1 = (unsigned int)__shfl_xor((int)u[4 * kh + 1], 32);
      unsigned int t2 = (unsigned int)__shfl_xor((int)u[4 * kh + 2], 32);
      unsigned int t3 = (unsigned int)__shfl_xor((int)u[4 * kh + 3], 32);
      unsigned int fr[4];
      fr[0] = hh ? t2 : u[4 * kh + 0];
      fr[1] = hh ? t3 : u[4 * kh + 1];
      fr[2] = hh ? u[4 * kh + 2] : t0;
      fr[3] = hh ? u[4 * kh + 3] : t1;
      bf16x8 pa = *reinterpret_cast<bf16x8*>(fr);
      bf16x8 v0 = *(const bf16x8*)(VT + ql * 32 + (((2 * kh + hh) ^ (ql & 3)) << 3));
      bf16x8 v1 = *(const bf16x8*)(VT + (32 + ql) * 32 + (((2 * kh + hh) ^ (ql & 3)) << 3));
      __builtin_amdgcn_s_setprio(1);
      pacc0 = __builtin_amdgcn_mfma_f32_32x32x16_bf16(pa, v0, pacc0, 0, 0, 0);
      pacc1 = __builtin_amdgcn_mfma_f32_32x32x16_bf16(pa, v1, pacc1, 0, 0, 0);
      __builtin_amdgcn_s_setprio(0);
    }
  }

  // ---- wave-local epilogue ----
  float lt = l_acc + __shfl_xor(l_acc, 32);
  if (lane < 32) linv_g[(size_t)bh * TLEN + qg] = 1.0f / lt;
  float inv = 1.0f / lt;
#pragma unroll
  for (int r = 0; r < 16; ++r) {
    int qrow = (r & 3) + 8 * (r >> 2) + 4 * hh;
    float iv = __shfl(inv, qrow);
    size_t aoff = ((size_t)(q0 + qrow) * NB + b) * DMODEL + h * NDH;
    av_bf[aoff + ql] = f2bf(pacc0[r] * iv);
    av_bf[aoff + 32 + ql] = f2bf(pacc1[r] * iv);
  }
}

// ---------------------------------------------------------------------------
// Transpose-rescale: S[bh][jp][q] (bf16 j-pairs) -> prob[bh][q][j] f32 * 1/l.
// ---------------------------------------------------------------------------

__global__ __launch_bounds__(256) void rescale_t(const unsigned int* __restrict__ S,
                                                 const float* __restrict__ linv_g,
                                                 float* __restrict__ prob) {
  __shared__ unsigned int lds[64][65];
  __shared__ float liv[64];
  const int qt = blockIdx.x;   // 32 tiles of 64 q
  const int jt = blockIdx.y;   // 16 tiles of 64 jp (=128 j)
  const int bh = blockIdx.z;
  const int t = threadIdx.x;

  const unsigned int* Sb = S + ((size_t)bh * (TLEN / 2) + jt * 64) * TLEN + qt * 64;
  {
    int row = t >> 2, c0 = (t & 3) * 16;
#pragma unroll
    for (int k = 0; k < 4; ++k) {
      uint4 v = *reinterpret_cast<const uint4*>(Sb + (size_t)row * TLEN + c0 + k * 4);
      lds[row][c0 + k * 4 + 0] = v.x;
      lds[row][c0 + k * 4 + 1] = v.y;
      lds[row][c0 + k * 4 + 2] = v.z;
      lds[row][c0 + k * 4 + 3] = v.w;
    }
  }
  if (t < 64) liv[t] = linv_g[(size_t)bh * TLEN + qt * 64 + t];
  __syncthreads();

  float* P = prob + ((size_t)bh * TLEN + qt * 64) * TLEN + jt * 128;
#pragma unroll
  for (int k = 0; k < 8; ++k) {
    int idx = k * 256 + t;             // 2048 float4 = 64 rows x 32
    int row = idx >> 5, c4 = idx & 31;
    unsigned int u0 = lds[c4 * 2][row];
    unsigned int u1 = lds[c4 * 2 + 1][row];
    float iv = liv[row];
    float4 o;
    o.x = bf2f((ushortT)(u0 & 0xffff)) * iv;
    o.y = bf2f((ushortT)(u0 >> 16)) * iv;
    o.z = bf2f((ushortT)(u1 & 0xffff)) * iv;
    o.w = bf2f((ushortT)(u1 >> 16)) * iv;
    *reinterpret_cast<float4*>(P + (size_t)row * TLEN + c4 * 4) = o;
  }
}

// ---------------------------------------------------------------------------
// FALLBACK attention (R7 structure, rk_ext indexing): fused rescale, staging
// inside prob. Used only if d_ws is too small for the S buffer.
// ---------------------------------------------------------------------------

__global__ __launch_bounds__(256) void attn_fused(
    const ushortT* __restrict__ qb, const ushortT* __restrict__ kb,
    const ushortT* __restrict__ vtb, const ushortT* __restrict__ rkE,
    const float* __restrict__ mfl, float* __restrict__ prob,
    ushortT* __restrict__ av_bf) {
  __shared__ float W[4][64][32];
  __shared__ float sl[4][32];
  __shared__ float linv[64];

  const int bh = blockIdx.y;
  const int b = bh >> 4, h = bh & 15;
  const int wv = threadIdx.x >> 6;
  const int lane = threadIdx.x & 63;
  const int ql = lane & 31;
  const int hh = lane >> 5;
  const int qtile = wv & 1;
  const int jh = wv >> 1;
  const int q0 = blockIdx.x * 64 + qtile * 32;
  const int qg = q0 + ql;

  const ushortT* Qbh = qb + (size_t)bh * TLEN * NDH;
  const ushortT* Kbh = kb + (size_t)bh * TLEN * NDH;
  const ushortT* Vbh = vtb + (size_t)bh * NDH * TLEN;
  const ushortT* Rh  = rkE + (size_t)h * 4096 * NDH;
  const float* mflb  = mfl + (size_t)b * TLEN;
  float (*Wp)[32] = W[wv];

  bf16x8 Qf[4], Qs[4];
  {
    int r2 = min(qg + 1, TLEN - 1);
#pragma unroll
    for (int c = 0; c < 4; ++c) {
      Qf[c] = *(const bf16x8*)(Qbh + (size_t)qg * NDH + c * 16 + hh * 8);
      Qs[c] = *(const bf16x8*)(Qbh + (size_t)r2 * NDH + c * 16 + hh * 8);
    }
  }

  f32x16 pacc0, pacc1;
#pragma unroll
  for (int i = 0; i < 16; ++i) { pacc0[i] = 0.f; pacc1[i] = 0.f; }
  float l_acc = 0.f;

  ushortT* pbrow = (ushortT*)prob + ((size_t)bh * TLEN + qg) * 4096 + 2048;

  const int jbeg = jh * (TLEN / 2);
  const int jend = jbeg + (TLEN / 2);
  for (int j0 = jbeg; j0 < jend; j0 += 32) {
    const int base_t = 2016 + j0 - q0;
    const bool t0w1 = (j0 <= q0);
    const bool t1w1 = (j0 < q0);

    const ushortT* s0 = Rh + (size_t)(base_t + ql) * NDH + hh * 8;
    const ushortT* s1 = Rh + (size_t)(base_t + 32 + ql) * NDH + hh * 8;
    const ushortT* sk = Kbh + (size_t)(j0 + ql) * NDH + hh * 8;
    const ushortT* vrow0 = Vbh + (size_t)ql * TLEN + j0 + 8 * hh;
    const ushortT* vrow1 = Vbh + (size_t)(32 + ql) * TLEN + j0 + 8 * hh;
    bf16x8 rk0[4], rk1[4], kk[4];
#pragma unroll
    for (int c = 0; c < 4; ++c) {
      rk0[c] = *(const bf16x8*)(s0 + c * 16);
      rk1[c] = *(const bf16x8*)(s1 + c * 16);
      kk[c]  = *(const bf16x8*)(sk + c * 16);
    }
    bf16x8 v00 = *(const bf16x8*)(vrow0);
    bf16x8 v01 = *(const bf16x8*)(vrow0 + 16);
    bf16x8 v10 = *(const bf16x8*)(vrow1);
    bf16x8 v11 = *(const bf16x8*)(vrow1 + 16);
    float4 mf4[4];
#pragma unroll
    for (int g = 0; g < 4; ++g)
      mf4[g] = *(const float4*)(mflb + j0 + 8 * g + 4 * hh);

    f32x16 facc;
#pragma unroll
    for (int i = 0; i < 16; ++i) facc[i] = 0.f;
    __builtin_amdgcn_s_setprio(1);
#pragma unroll
    for (int c = 0; c < 4; ++c)
      facc = __builtin_amdgcn_mfma_f32_32x32x16_bf16(rk0[c], t0w1 ? Qf[c] : Qs[c], facc, 0, 0, 0);
    __builtin_amdgcn_s_setprio(0);
#pragma unroll
    for (int r = 0; r < 16; ++r)
      Wp[(r & 3) + 8 * (r >> 2) + 4 * hh][ql] = facc[r];

#pragma unroll
    for (int i = 0; i < 16; ++i) facc[i] = 0.f;
    __builtin_amdgcn_s_setprio(1);
#pragma unroll
    for (int c = 0; c < 4; ++c)
      facc = __builtin_amdgcn_mfma_f32_32x32x16_bf16(rk1[c], t1w1 ? Qf[c] : Qs[c], facc, 0, 0, 0);
    __builtin_amdgcn_s_setprio(0);
#pragma unroll
    for (int r = 0; r < 16; ++r)
      Wp[32 + (r & 3) + 8 * (r >> 2) + 4 * hh][ql] = facc[r];

    f32x16 cacc;
#pragma unroll
    for (int i = 0; i < 16; ++i) cacc[i] = 0.f;
    __builtin_amdgcn_s_setprio(1);
#pragma unroll
    for (int c = 0; c < 4; ++c)
      cacc = __builtin_amdgcn_mfma_f32_32x32x16_bf16(kk[c], Qf[c], cacc, 0, 0, 0);
    __builtin_amdgcn_s_setprio(0);

    float p[16];
#pragma unroll
    for (int r = 0; r < 16; ++r) {
      int jrow = (r & 3) + 8 * (r >> 2) + 4 * hh;
      float bd = Wp[jrow - ql + 31][ql];
      float sc = (cacc[r] + bd) * 0.125f;
      float mv = (&mf4[r >> 2].x)[r & 3];
      float pv = mv * __expf(sc);
      p[r] = pv;
      l_acc += pv;
    }

#pragma unroll
    for (int g = 0; g < 4; ++g) {
      uint2 st;
      st.x = pk2(p[4 * g + 0], p[4 * g + 1]);
      st.y = pk2(p[4 * g + 2], p[4 * g + 3]);
      *reinterpret_cast<uint2*>(pbrow + j0 + 8 * g + 4 * hh) = st;
    }

#pragma unroll
    for (int kh = 0; kh < 2; ++kh) {
      unsigned int u0 = pk2(p[8 * kh + 0], p[8 * kh + 1]);
      unsigned int u1 = pk2(p[8 * kh + 2], p[8 * kh + 3]);
      unsigned int u2 = pk2(p[8 * kh + 4], p[8 * kh + 5]);
      unsigned int u3 = pk2(p[8 * kh + 6], p[8 * kh + 7]);
      unsigned int t0 = (unsigned int)__shfl_xor((int)u0, 32);
      unsigned int t1 = (unsigned int)__shfl_xor((int)u1, 32);
      unsigned int t2 = (unsigned int)__shfl_xor((int)u2, 32);
      unsigned int t3 = (unsigned int)__shfl_xor((int)u3, 32);
      unsigned int fr[4];
      fr[0] = hh ? t2 : u0;
      fr[1] = hh ? t3 : u1;
      fr[2] = hh ? u2 : t0;
      fr[3] = hh ? u3 : t1;
      bf16x8 pa = *reinterpret_cast<bf16x8*>(fr);
      __builtin_amdgcn_s_setprio(1);
      pacc0 = __builtin_amdgcn_mfma_f32_32x32x16_bf16(pa, kh ? v01 : v00, pacc0, 0, 0, 0);
      pacc1 = __builtin_amdgcn_mfma_f32_32x32x16_bf16(pa, kh ? v11 : v10, pacc1, 0, 0, 0);
      __builtin_amdgcn_s_setprio(0);
    }
  }

#pragma unroll
  for (int r = 0; r < 16; ++r) {
    int qrow = (r & 3) + 8 * (r >> 2) + 4 * hh;
    Wp[qrow][ql] = pacc0[r];
    Wp[32 + qrow][ql] = pacc1[r];
  }
  float lh = l_acc + __shfl_xor(l_acc, 32);
  if (lane < 32) sl[wv][ql] = lh;
  __syncthreads();

  if (wv < 2) {
    if (lane < 32) {
      float lt = sl[wv][ql] + sl[wv + 2][ql];
      linv[wv * 32 + ql] = 1.0f / lt;
    }
#pragma unroll
    for (int r = 0; r < 16; ++r) {
      int qrow = (r & 3) + 8 * (r >> 2) + 4 * hh;
      float lt = sl[wv][qrow] + sl[wv + 2][qrow];
      float iv = 1.0f / lt;
      float s0v = W[wv][qrow][ql] + W[wv + 2][qrow][ql];
      float s1v = W[wv][32 + qrow][ql] + W[wv + 2][32 + qrow][ql];
      size_t aoff = ((size_t)(q0 + qrow) * NB + b) * DMODEL + h * NDH;
      av_bf[aoff + ql] = f2bf(s0v * iv);
      av_bf[aoff + 32 + ql] = f2bf(s1v * iv);
    }
  }
  __syncthreads();

  const ushortT* probus = (const ushortT*)prob;
  const int lr = lane >> 4;
  const int cg = lane & 15;
  for (int s = 0; s < 8; ++s) {
    const int rloc = qtile * 32 + s * 4 + lr;
    const int rowg = blockIdx.x * 64 + rloc;
    const size_t ub = ((size_t)bh * TLEN + rowg) * 4096 + 2048 + jh * 1024 + cg * 8;
    const size_t fb = ((size_t)bh * TLEN + rowg) * 2048 + jh * 1024 + cg * 8;
    uint4 a[8];
#pragma unroll
    for (int k = 0; k < 8; ++k)
      a[k] = *reinterpret_cast<const uint4*>(probus + ub + k * 128);
    const float iv = linv[rloc];
    __syncthreads();
#pragma unroll
    for (int k = 0; k < 8; ++k) {
      float4 o0, o1;
      o0.x = bf2f((ushortT)(a[k].x & 0xffff)) * iv;
      o0.y = bf2f((ushortT)(a[k].x >> 16)) * iv;
      o0.z = bf2f((ushortT)(a[k].y & 0xffff)) * iv;
      o0.w = bf2f((ushortT)(a[k].y >> 16)) * iv;
      o1.x = bf2f((ushortT)(a[k].z & 0xffff)) * iv;
      o1.y = bf2f((ushortT)(a[k].z >> 16)) * iv;
      o1.z = bf2f((ushortT)(a[k].w & 0xffff)) * iv;
      o1.w = bf2f((ushortT)(a[k].w >> 16)) * iv;
      *reinterpret_cast<float4*>(prob + fb + k * 128) = o0;
      *reinterpret_cast<float4*>(prob + fb + k * 128 + 4) = o1;
    }
  }
}

// ---------------------------------------------------------------------------

extern "C" void kernel_launch(void* const* d_in, const int* in_sizes, int n_in,
                              void* d_out, int out_size, void* d_ws, size_t ws_size,
                              hipStream_t stream) {
  const float* w      = (const float*)d_in[0];   // (T,B,D)
  const float* r      = (const float*)d_in[1];   // (T,D)
  const float* w_qkv  = (const float*)d_in[2];   // (3072,1024)
  const float* w_r    = (const float*)d_in[3];   // (1024,1024)
  const float* w_o    = (const float*)d_in[4];   // (1024,1024)
  const float* bias   = (const float*)d_in[5];   // (16,64)
  const int* mask     = (const int*)d_in[6];     // (T,B) int32

  float* out  = (float*)d_out;
  float* prob = out + (size_t)TLEN * NB * DMODEL;

  const size_t SZ = (size_t)NB * NH * TLEN * NDH;        // 4194304
  ushortT* w_bf    = (ushortT*)d_ws;
  ushortT* wqkv_bf = w_bf + (size_t)4096 * 1024;
  ushortT* r_bf    = wqkv_bf + (size_t)3072 * 1024;
  ushortT* wr_bf   = r_bf + (size_t)2048 * 1024;
  ushortT* wo_bf   = wr_bf + (size_t)1024 * 1024;
  ushortT* q_bf    = wo_bf + (size_t)1024 * 1024;
  ushortT* k_bf    = q_bf + SZ;
  ushortT* vt_bf   = k_bf + SZ;
  ushortT* rkE_bf  = vt_bf + SZ;                         // 16*4096*64
  ushortT* av_bf   = rkE_bf + (size_t)NH * 4096 * NDH;
  float* mfl       = (float*)(av_bf + SZ);
  float* linv_g    = mfl + (size_t)NB * TLEN;
  unsigned int* S  = (unsigned int*)(linv_g + (size_t)NB * NH * TLEN);
  const size_t need = (size_t)((char*)(S + (size_t)NB * NH * (TLEN / 2) * TLEN) -
                               (char*)d_ws);
  const bool fast = ws_size >= need;

  cvt_bf16<<<4096, 256, 0, stream>>>(w, w_bf, 4096 * 1024 / 4);
  cvt_bf16<<<3072, 256, 0, stream>>>(w_qkv, wqkv_bf, 3072 * 1024 / 4);
  cvt_bf16<<<2048, 256, 0, stream>>>(r, r_bf, 2048 * 1024 / 4);
  cvt_bf16<<<1024, 256, 0, stream>>>(w_r, wr_bf, 1024 * 1024 / 4);
  cvt_bf16<<<1024, 256, 0, stream>>>(w_o, wo_bf, 1024 * 1024 / 4);
  cvt_mask<<<8, 256, 0, stream>>>(mask, mfl);
  zero_rkext<<<1, 256, 0, stream>>>(rkE_bf);

  EpiQKV e1{q_bf, k_bf, vt_bf, bias};
  gemm_bf16<EpiQKV><<<dim3(3072 / 128, 4096 / 128), 256, 0, stream>>>(w_bf, wqkv_bf, DMODEL, e1);
  EpiRK e2{rkE_bf};
  gemm_bf16<EpiRK><<<dim3(1024 / 128, 2048 / 128), 256, 0, stream>>>(r_bf, wr_bf, DMODEL, e2);

  if (fast) {
    attn_fast<<<dim3(32, 32), 128, 0, stream>>>(q_bf, k_bf, vt_bf, rkE_bf,
                                                mfl, S, linv_g, av_bf);
    rescale_t<<<dim3(32, 16, 32), 256, 0, stream>>>(S, linv_g, prob);
  } else {
    attn_fused<<<dim3(32, 32), 256, 0, stream>>>(q_bf, k_bf, vt_bf, rkE_bf,
                                                 mfl, prob, av_bf);
  }

  EpiOut e5{out};
  gemm_bf16<EpiOut><<<dim3(1024 / 128, 4096 / 128), 256, 0, stream>>>(av_bf, wo_bf, DMODEL, e5);
}

// Round 10
// 444.608 us; speedup vs baseline: 2.6474x; 1.0600x over previous
//
#include <hip/hip_runtime.h>
#include <hip/hip_bf16.h>
#include <cstdint>
#include <cstddef>

#define TLEN 2048
#define NB 2
#define DMODEL 1024
#define NH 16
#define NDH 64

typedef unsigned short ushortT;
typedef short bf16x8 __attribute__((ext_vector_type(8)));
typedef float f32x16 __attribute__((ext_vector_type(16)));

__device__ __forceinline__ ushortT f2bf(float f) {
  union { float f; unsigned int u; } x{f};
  unsigned int r = x.u + 0x7fff + ((x.u >> 16) & 1);   // RNE
  return (ushortT)(r >> 16);
}
__device__ __forceinline__ unsigned int pk2(float lo, float hi) {
  return ((unsigned int)f2bf(hi) << 16) | (unsigned int)f2bf(lo);
}
__device__ __forceinline__ float bf2f(ushortT u) {
  union { unsigned int u; float f; } x;
  x.u = ((unsigned int)u) << 16;
  return x.f;
}

__device__ __forceinline__ void gld_lds16(const void* g, void* l) {
  __builtin_amdgcn_global_load_lds(
      (const __attribute__((address_space(1))) unsigned int*)g,
      (__attribute__((address_space(3))) unsigned int*)l, 16, 0, 0);
}

// ---------------------------------------------------------------------------
// fused prologue: all f32->bf16 converts + mask floats + rk_ext zero row
// ---------------------------------------------------------------------------

__global__ __launch_bounds__(256) void cvt_all(
    const float* __restrict__ w, const float* __restrict__ wqkv,
    const float* __restrict__ r, const float* __restrict__ wr,
    const float* __restrict__ wo, ushortT* __restrict__ w_bf,
    ushortT* __restrict__ wqkv_bf, ushortT* __restrict__ r_bf,
    ushortT* __restrict__ wr_bf, ushortT* __restrict__ wo_bf,
    const int* __restrict__ mask, float* __restrict__ mfl,
    ushortT* __restrict__ rkE) {
  const size_t N0 = 1048576, N1 = N0 + 786432, N2 = N1 + 524288,
               N3 = N2 + 262144, N4 = N3 + 262144;
  size_t i = (size_t)blockIdx.x * 256 + threadIdx.x;
  const float* src; ushortT* dst; size_t off;
  if (i < N0)      { src = w;    dst = w_bf;    off = i; }
  else if (i < N1) { src = wqkv; dst = wqkv_bf; off = i - N0; }
  else if (i < N2) { src = r;    dst = r_bf;    off = i - N1; }
  else if (i < N3) { src = wr;   dst = wr_bf;   off = i - N2; }
  else if (i < N4) { src = wo;   dst = wo_bf;   off = i - N3; }
  else {
    size_t k = i - N4;
    if (k < 512) {                       // mask floats: 4 j per thread
      int j = (int)k * 4;
#pragma unroll
      for (int s = 0; s < 4; ++s) {
        mfl[j + s]        = mask[(size_t)(j + s) * NB]     ? 0.f : 1.f;
        mfl[TLEN + j + s] = mask[(size_t)(j + s) * NB + 1] ? 0.f : 1.f;
      }
    } else if (k < 512 + 256) {          // rk_ext zero row per head
      int ii = (int)k - 512; int h = ii >> 4, c = ii & 15;
      ushort4 z; z.x = 0; z.y = 0; z.z = 0; z.w = 0;
      *reinterpret_cast<ushort4*>(rkE + ((size_t)h * 4096 + 2048) * NDH + c * 4) = z;
    }
    return;
  }
  float4 v = reinterpret_cast<const float4*>(src)[off];
  ushort4 o;
  o.x = f2bf(v.x); o.y = f2bf(v.y); o.z = f2bf(v.z); o.w = f2bf(v.w);
  reinterpret_cast<ushort4*>(dst)[off] = o;
}

// ---------------------------------------------------------------------------
// bf16 MFMA GEMM (unchanged)
// ---------------------------------------------------------------------------

template <typename Epi>
__global__ __launch_bounds__(256) void gemm_bf16(const ushortT* __restrict__ A,
                                                 const ushortT* __restrict__ B,
                                                 int K, Epi epi) {
  __shared__ ushortT Al[128 * 64];
  __shared__ ushortT Bl[128 * 64];
  const int tid = threadIdx.x;
  const int lane = tid & 63;
  const int wv = tid >> 6;
  const int wm = wv >> 1, wn = wv & 1;
  const int m0 = blockIdx.y * 128;
  const int n0 = blockIdx.x * 128;
  const int r32 = lane & 31;
  const int hh = lane >> 5;

  f32x16 acc[2][2];
#pragma unroll
  for (int i = 0; i < 2; ++i)
#pragma unroll
    for (int j = 0; j < 2; ++j)
#pragma unroll
      for (int e = 0; e < 16; ++e) acc[i][j][e] = 0.f;

  for (int k0 = 0; k0 < K; k0 += 64) {
#pragma unroll
    for (int it = 0; it < 4; ++it) {
      int idx = it * 256 + tid;          // 1024 chunks of 16B
      int r = idx >> 3, c = idx & 7;
      int gcol = k0 + ((c ^ (r & 7)) << 3);
      gld_lds16(A + (size_t)(m0 + r) * K + gcol, Al + idx * 8);
      gld_lds16(B + (size_t)(n0 + r) * K + gcol, Bl + idx * 8);
    }
    asm volatile("s_waitcnt vmcnt(0)");
    __syncthreads();
#pragma unroll
    for (int kc = 0; kc < 4; ++kc) {
      int lc = kc * 2 + hh;              // logical 16B chunk in row
      bf16x8 af[2], bfr[2];
#pragma unroll
      for (int f = 0; f < 2; ++f) {
        int ar = wm * 64 + f * 32 + r32;
        af[f] = *(const bf16x8*)(Al + ar * 64 + ((lc ^ (ar & 7)) << 3));
        int br = wn * 64 + f * 32 + r32;
        bfr[f] = *(const bf16x8*)(Bl + br * 64 + ((lc ^ (br & 7)) << 3));
      }
#pragma unroll
      for (int i = 0; i < 2; ++i)
#pragma unroll
        for (int j = 0; j < 2; ++j)
          acc[i][j] = __builtin_amdgcn_mfma_f32_32x32x16_bf16(af[i], bfr[j],
                                                              acc[i][j], 0, 0, 0);
    }
    __syncthreads();
  }

#pragma unroll
  for (int i = 0; i < 2; ++i)
#pragma unroll
    for (int j = 0; j < 2; ++j)
#pragma unroll
      for (int rg = 0; rg < 16; ++rg) {
        int m = m0 + wm * 64 + i * 32 + (rg & 3) + 8 * (rg >> 2) + 4 * hh;
        int n = n0 + wn * 64 + j * 32 + r32;
        epi.store(m, n, acc[i][j][rg]);
      }
}

struct EpiQKV {
  ushortT* qb; ushortT* kb; ushortT* vtb; const float* bias;
  __device__ void store(int m, int n, float val) const {
    int t = m >> 1, b = m & 1;
    int which = n >> 10;
    int h = (n >> 6) & (NH - 1);
    int dh = n & (NDH - 1);
    int bh = b * NH + h;
    if (which == 0)
      qb[((size_t)bh * TLEN + t) * NDH + dh] = f2bf(val + bias[(h << 6) | dh]);
    else if (which == 1)
      kb[((size_t)bh * TLEN + t) * NDH + dh] = f2bf(val);
    else
      vtb[((size_t)bh * NDH + dh) * TLEN + t] = f2bf(val);
  }
};

struct EpiRK {   // rk_ext: row m = rk[m] (m<=2047); row 2048 = 0 (cvt_all);
                 // row m = rk[m-2049] (m>=2049)
  ushortT* rkE;
  __device__ void store(int m, int n, float val) const {
    int h = n >> 6, dh = n & 63;
    ushortT v = f2bf(val);
    rkE[((size_t)h * 4096 + m) * NDH + dh] = v;
    if (m <= 2046)
      rkE[((size_t)h * 4096 + m + 2049) * NDH + dh] = v;
  }
};

struct EpiOut {
  float* out;
  __device__ void store(int m, int n, float val) const {
    out[(size_t)m * DMODEL + n] = val;
  }
};

// ---------------------------------------------------------------------------
// FAST attention, LDS-staged + software-pipelined (single buffer).
// Grid (32,32): blockIdx.y = bh, blockIdx.x = 64 q rows; 2 waves/block.
// Per 32-j chunk:
//   [staging for this chunk already in flight from previous iteration]
//   vmcnt(8)+barrier (tail of prev iter) -> tiles visible
//   mf4 loads; 16x ds_read_b128 fragments (RK/KT/VT) -> regs
//   lgkmcnt(0)+barrier -> tiles free
//   issue next chunk's global_load_lds (10/wave, stay in flight over compute)
//   MFMA BD1/BD2 -> W; MFMA AC; gather+exp; S stores; PV MFMA (V in regs)
// Tail: vmcnt(8) waits only the 10 staging loads (8 S-stores may linger).
// ---------------------------------------------------------------------------

__global__ __launch_bounds__(128) void attn_fast(
    const ushortT* __restrict__ qb, const ushortT* __restrict__ kb,
    const ushortT* __restrict__ vtb, const ushortT* __restrict__ rkE,
    const float* __restrict__ mfl, unsigned int* __restrict__ S,
    float* __restrict__ linv_g, ushortT* __restrict__ av_bf) {
  __shared__ float W[2][64][32];
  __shared__ ushortT KT[2048];   // [32 j][8 x 16B chunks], chunk c at c^(row&7)
  __shared__ ushortT VT[2048];   // [64 d][4 x 16B chunks], chunk c at c^(d&3)
  __shared__ ushortT RK[6144];   // [96 rows][8 chunks],    chunk c at c^(row&7)

  const int bh = blockIdx.y;
  const int b = bh >> 4, h = bh & 15;
  const int t = threadIdx.x >> 6;        // q-tile wave
  const int lane = threadIdx.x & 63;
  const int ql = lane & 31;
  const int hh = lane >> 5;
  const int Q0 = blockIdx.x * 64;
  const int q0 = Q0 + 32 * t;
  const int qg = q0 + ql;

  const ushortT* Qbh = qb + (size_t)bh * TLEN * NDH;
  const ushortT* Kbh = kb + (size_t)bh * TLEN * NDH;
  const ushortT* Vbh = vtb + (size_t)bh * NDH * TLEN;
  const ushortT* Rh  = rkE + (size_t)h * 4096 * NDH;
  const float* mflb  = mfl + (size_t)b * TLEN;
  unsigned int* Sb   = S + (size_t)bh * (TLEN / 2) * TLEN;
  float (*Wp)[32] = W[t];

  auto STAGE = [&](int j0) {
    const int U = 1984 + j0 - Q0;        // in [0, 4000]; U+96 <= 4096
#pragma unroll
    for (int i = 0; i < 6; ++i) {        // RK: 6 insts/wave
      int ci = (t * 6 + i) * 64 + lane;
      int row = ci >> 3, c = ci & 7;
      gld_lds16(Rh + (size_t)(U + row) * NDH + ((c ^ (row & 7)) << 3), RK + ci * 8);
    }
#pragma unroll
    for (int i = 0; i < 2; ++i) {        // KT + VT: 2+2 insts/wave
      int ci = (t * 2 + i) * 64 + lane;
      int row = ci >> 3, c = ci & 7;
      gld_lds16(Kbh + (size_t)(j0 + row) * NDH + ((c ^ (row & 7)) << 3), KT + ci * 8);
      int d = ci >> 2, c2 = ci & 3;
      gld_lds16(Vbh + (size_t)d * TLEN + j0 + ((c2 ^ (d & 3)) << 3), VT + ci * 8);
    }
  };

  bf16x8 Qf[4], Qs[4];
  {
    int r2 = min(qg + 1, TLEN - 1);
#pragma unroll
    for (int c = 0; c < 4; ++c) {
      Qf[c] = *(const bf16x8*)(Qbh + (size_t)qg * NDH + c * 16 + hh * 8);
      Qs[c] = *(const bf16x8*)(Qbh + (size_t)r2 * NDH + c * 16 + hh * 8);
    }
  }

  f32x16 pacc0, pacc1;
#pragma unroll
  for (int i = 0; i < 16; ++i) { pacc0[i] = 0.f; pacc1[i] = 0.f; }
  float l_acc = 0.f;

  // prologue: stage chunk 0, full drain
  STAGE(0);
  asm volatile("s_waitcnt vmcnt(0)");
  __builtin_amdgcn_s_barrier();

  for (int j0 = 0; j0 < TLEN; j0 += 32) {
    // current-chunk mask loads (oldest VMEM after stores -> cheap wait at exp)
    float4 mf4[4];
#pragma unroll
    for (int g = 0; g < 4; ++g)
      mf4[g] = *(const float4*)(mflb + j0 + 8 * g + 4 * hh);

    // ---- fragment ds_reads -> registers ----
    const int R1 = 32 * (1 - t) + ql;
    const int R2 = R1 + 32;
    bf16x8 a1[4], a2[4], ak[4];
#pragma unroll
    for (int c = 0; c < 4; ++c) {
      a1[c] = *(const bf16x8*)(RK + R1 * 64 + (((2 * c + hh) ^ (R1 & 7)) << 3));
      a2[c] = *(const bf16x8*)(RK + R2 * 64 + (((2 * c + hh) ^ (R2 & 7)) << 3));
      ak[c] = *(const bf16x8*)(KT + ql * 64 + (((2 * c + hh) ^ (ql & 7)) << 3));
    }
    bf16x8 vv0[2], vv1[2];
#pragma unroll
    for (int kh = 0; kh < 2; ++kh) {
      vv0[kh] = *(const bf16x8*)(VT + ql * 32 + (((2 * kh + hh) ^ (ql & 3)) << 3));
      vv1[kh] = *(const bf16x8*)(VT + (32 + ql) * 32 + (((2 * kh + hh) ^ (ql & 3)) << 3));
    }
    asm volatile("s_waitcnt lgkmcnt(0)");
    __builtin_amdgcn_s_barrier();        // tiles free to overwrite

    if (j0 + 32 < TLEN) STAGE(j0 + 32);  // async, hidden under compute below

    const bool t0w1 = (j0 <= q0);
    const bool t1w1 = (j0 < q0);

    // BD tile 1 -> W rows [0,32)
    f32x16 facc;
#pragma unroll
    for (int i = 0; i < 16; ++i) facc[i] = 0.f;
    __builtin_amdgcn_s_setprio(1);
#pragma unroll
    for (int c = 0; c < 4; ++c)
      facc = __builtin_amdgcn_mfma_f32_32x32x16_bf16(a1[c], t0w1 ? Qf[c] : Qs[c], facc, 0, 0, 0);
    __builtin_amdgcn_s_setprio(0);
#pragma unroll
    for (int r = 0; r < 16; ++r)
      Wp[(r & 3) + 8 * (r >> 2) + 4 * hh][ql] = facc[r];

    // BD tile 2 -> W rows [32,64)
#pragma unroll
    for (int i = 0; i < 16; ++i) facc[i] = 0.f;
    __builtin_amdgcn_s_setprio(1);
#pragma unroll
    for (int c = 0; c < 4; ++c)
      facc = __builtin_amdgcn_mfma_f32_32x32x16_bf16(a2[c], t1w1 ? Qf[c] : Qs[c], facc, 0, 0, 0);
    __builtin_amdgcn_s_setprio(0);
#pragma unroll
    for (int r = 0; r < 16; ++r)
      Wp[32 + (r & 3) + 8 * (r >> 2) + 4 * hh][ql] = facc[r];

    // AC tile (S^T)
    f32x16 cacc;
#pragma unroll
    for (int i = 0; i < 16; ++i) cacc[i] = 0.f;
    __builtin_amdgcn_s_setprio(1);
#pragma unroll
    for (int c = 0; c < 4; ++c)
      cacc = __builtin_amdgcn_mfma_f32_32x32x16_bf16(ak[c], Qf[c], cacc, 0, 0, 0);
    __builtin_amdgcn_s_setprio(0);

    float p[16];
#pragma unroll
    for (int r = 0; r < 16; ++r) {
      int jrow = (r & 3) + 8 * (r >> 2) + 4 * hh;
      float bd = Wp[jrow - ql + 31][ql];
      float sc = (cacc[r] + bd) * 0.125f;
      float mv = (&mf4[r >> 2].x)[r & 3];
      float pv = mv * __expf(sc);
      p[r] = pv;
      l_acc += pv;
    }

    unsigned int u[8];
#pragma unroll
    for (int i = 0; i < 8; ++i) u[i] = pk2(p[2 * i], p[2 * i + 1]);

    // coalesced transposed staging: S[bh][(j0+jrow)/2][qg]
#pragma unroll
    for (int i = 0; i < 8; ++i) {
      int r = 2 * i;
      int jrow = (r & 3) + 8 * (r >> 2) + 4 * hh;   // even
      Sb[(size_t)((j0 + jrow) >> 1) * TLEN + qg] = u[i];
    }

#pragma unroll
    for (int kh = 0; kh < 2; ++kh) {
      unsigned int t0 = (unsigned int)__shfl_xor((int)u[4 * kh + 0], 32);
      unsigned int t1 = (unsigned int)__shfl_xor((int)u[4 * kh + 1], 32);
      unsigned int t2 = (unsigned int)__shfl_xor((int)u[4 * kh + 2], 32);
      unsigned int t3 = (unsigned int)__shfl_xor((int)u[4 * kh + 3], 32);
      unsigned int fr[4];
      fr[0] = hh ? t2 : u[4 * kh + 0];
      fr[1] = hh ? t3 : u[4 * kh + 1];
      fr[2] = hh ? u[4 * kh + 2] : t0;
      fr[3] = hh ? u[4 * kh + 3] : t1;
      bf16x8 pa = *reinterpret_cast<bf16x8*>(fr);
      __builtin_amdgcn_s_setprio(1);
      pacc0 = __builtin_amdgcn_mfma_f32_32x32x16_bf16(pa, kh ? vv0[1] : vv0[0], pacc0, 0, 0, 0);
      pacc1 = __builtin_amdgcn_mfma_f32_32x32x16_bf16(pa, kh ? vv1[1] : vv1[0], pacc1, 0, 0, 0);
      __builtin_amdgcn_s_setprio(0);
    }

    if (j0 + 32 < TLEN) {
      // wait the 10 staging loads (oldest); S stores may stay in flight
      asm volatile("s_waitcnt vmcnt(8)");
      __builtin_amdgcn_s_barrier();      // next chunk's tiles visible
    }
  }

  // ---- wave-local epilogue ----
  float lt = l_acc + __shfl_xor(l_acc, 32);
  if (lane < 32) linv_g[(size_t)bh * TLEN + qg] = 1.0f / lt;
  float inv = 1.0f / lt;
#pragma unroll
  for (int r = 0; r < 16; ++r) {
    int qrow = (r & 3) + 8 * (r >> 2) + 4 * hh;
    float iv = __shfl(inv, qrow);
    size_t aoff = ((size_t)(q0 + qrow) * NB + b) * DMODEL + h * NDH;
    av_bf[aoff + ql] = f2bf(pacc0[r] * iv);
    av_bf[aoff + 32 + ql] = f2bf(pacc1[r] * iv);
  }
}

// ---------------------------------------------------------------------------
// Transpose-rescale: S[bh][jp][q] (bf16 j-pairs) -> prob[bh][q][j] f32 * 1/l.
// ---------------------------------------------------------------------------

__global__ __launch_bounds__(256) void rescale_t(const unsigned int* __restrict__ S,
                                                 const float* __restrict__ linv_g,
                                                 float* __restrict__ prob) {
  __shared__ unsigned int lds[64][65];
  __shared__ float liv[64];
  const int qt = blockIdx.x;   // 32 tiles of 64 q
  const int jt = blockIdx.y;   // 16 tiles of 64 jp (=128 j)
  const int bh = blockIdx.z;
  const int t = threadIdx.x;

  const unsigned int* Sb = S + ((size_t)bh * (TLEN / 2) + jt * 64) * TLEN + qt * 64;
  {
    int row = t >> 2, c0 = (t & 3) * 16;
#pragma unroll
    for (int k = 0; k < 4; ++k) {
      uint4 v = *reinterpret_cast<const uint4*>(Sb + (size_t)row * TLEN + c0 + k * 4);
      lds[row][c0 + k * 4 + 0] = v.x;
      lds[row][c0 + k * 4 + 1] = v.y;
      lds[row][c0 + k * 4 + 2] = v.z;
      lds[row][c0 + k * 4 + 3] = v.w;
    }
  }
  if (t < 64) liv[t] = linv_g[(size_t)bh * TLEN + qt * 64 + t];
  __syncthreads();

  float* P = prob + ((size_t)bh * TLEN + qt * 64) * TLEN + jt * 128;
#pragma unroll
  for (int k = 0; k < 8; ++k) {
    int idx = k * 256 + t;             // 2048 float4 = 64 rows x 32
    int row = idx >> 5, c4 = idx & 31;
    unsigned int u0 = lds[c4 * 2][row];
    unsigned int u1 = lds[c4 * 2 + 1][row];
    float iv = liv[row];
    float4 o;
    o.x = bf2f((ushortT)(u0 & 0xffff)) * iv;
    o.y = bf2f((ushortT)(u0 >> 16)) * iv;
    o.z = bf2f((ushortT)(u1 & 0xffff)) * iv;
    o.w = bf2f((ushortT)(u1 >> 16)) * iv;
    *reinterpret_cast<float4*>(P + (size_t)row * TLEN + c4 * 4) = o;
  }
}

// ---------------------------------------------------------------------------
// FALLBACK attention (unchanged R8 structure): fused rescale, staging inside
// prob. Used only if d_ws is too small for the S buffer.
// ---------------------------------------------------------------------------

__global__ __launch_bounds__(256) void attn_fused(
    const ushortT* __restrict__ qb, const ushortT* __restrict__ kb,
    const ushortT* __restrict__ vtb, const ushortT* __restrict__ rkE,
    const float* __restrict__ mfl, float* __restrict__ prob,
    ushortT* __restrict__ av_bf) {
  __shared__ float W[4][64][32];
  __shared__ float sl[4][32];
  __shared__ float linv[64];

  const int bh = blockIdx.y;
  const int b = bh >> 4, h = bh & 15;
  const int wv = threadIdx.x >> 6;
  const int lane = threadIdx.x & 63;
  const int ql = lane & 31;
  const int hh = lane >> 5;
  const int qtile = wv & 1;
  const int jh = wv >> 1;
  const int q0 = blockIdx.x * 64 + qtile * 32;
  const int qg = q0 + ql;

  const ushortT* Qbh = qb + (size_t)bh * TLEN * NDH;
  const ushortT* Kbh = kb + (size_t)bh * TLEN * NDH;
  const ushortT* Vbh = vtb + (size_t)bh * NDH * TLEN;
  const ushortT* Rh  = rkE + (size_t)h * 4096 * NDH;
  const float* mflb  = mfl + (size_t)b * TLEN;
  float (*Wp)[32] = W[wv];

  bf16x8 Qf[4], Qs[4];
  {
    int r2 = min(qg + 1, TLEN - 1);
#pragma unroll
    for (int c = 0; c < 4; ++c) {
      Qf[c] = *(const bf16x8*)(Qbh + (size_t)qg * NDH + c * 16 + hh * 8);
      Qs[c] = *(const bf16x8*)(Qbh + (size_t)r2 * NDH + c * 16 + hh * 8);
    }
  }

  f32x16 pacc0, pacc1;
#pragma unroll
  for (int i = 0; i < 16; ++i) { pacc0[i] = 0.f; pacc1[i] = 0.f; }
  float l_acc = 0.f;

  ushortT* pbrow = (ushortT*)prob + ((size_t)bh * TLEN + qg) * 4096 + 2048;

  const int jbeg = jh * (TLEN / 2);
  const int jend = jbeg + (TLEN / 2);
  for (int j0 = jbeg; j0 < jend; j0 += 32) {
    const int base_t = 2016 + j0 - q0;
    const bool t0w1 = (j0 <= q0);
    const bool t1w1 = (j0 < q0);

    const ushortT* s0 = Rh + (size_t)(base_t + ql) * NDH + hh * 8;
    const ushortT* s1 = Rh + (size_t)(base_t + 32 + ql) * NDH + hh * 8;
    const ushortT* sk = Kbh + (size_t)(j0 + ql) * NDH + hh * 8;
    const ushortT* vrow0 = Vbh + (size_t)ql * TLEN + j0 + 8 * hh;
    const ushortT* vrow1 = Vbh + (size_t)(32 + ql) * TLEN + j0 + 8 * hh;
    bf16x8 rk0[4], rk1[4], kk[4];
#pragma unroll
    for (int c = 0; c < 4; ++c) {
      rk0[c] = *(const bf16x8*)(s0 + c * 16);
      rk1[c] = *(const bf16x8*)(s1 + c * 16);
      kk[c]  = *(const bf16x8*)(sk + c * 16);
    }
    bf16x8 v00 = *(const bf16x8*)(vrow0);
    bf16x8 v01 = *(const bf16x8*)(vrow0 + 16);
    bf16x8 v10 = *(const bf16x8*)(vrow1);
    bf16x8 v11 = *(const bf16x8*)(vrow1 + 16);
    float4 mf4[4];
#pragma unroll
    for (int g = 0; g < 4; ++g)
      mf4[g] = *(const float4*)(mflb + j0 + 8 * g + 4 * hh);

    f32x16 facc;
#pragma unroll
    for (int i = 0; i < 16; ++i) facc[i] = 0.f;
    __builtin_amdgcn_s_setprio(1);
#pragma unroll
    for (int c = 0; c < 4; ++c)
      facc = __builtin_amdgcn_mfma_f32_32x32x16_bf16(rk0[c], t0w1 ? Qf[c] : Qs[c], facc, 0, 0, 0);
    __builtin_amdgcn_s_setprio(0);
#pragma unroll
    for (int r = 0; r < 16; ++r)
      Wp[(r & 3) + 8 * (r >> 2) + 4 * hh][ql] = facc[r];

#pragma unroll
    for (int i = 0; i < 16; ++i) facc[i] = 0.f;
    __builtin_amdgcn_s_setprio(1);
#pragma unroll
    for (int c = 0; c < 4; ++c)
      facc = __builtin_amdgcn_mfma_f32_32x32x16_bf16(rk1[c], t1w1 ? Qf[c] : Qs[c], facc, 0, 0, 0);
    __builtin_amdgcn_s_setprio(0);
#pragma unroll
    for (int r = 0; r < 16; ++r)
      Wp[32 + (r & 3) + 8 * (r >> 2) + 4 * hh][ql] = facc[r];

    f32x16 cacc;
#pragma unroll
    for (int i = 0; i < 16; ++i) cacc[i] = 0.f;
    __builtin_amdgcn_s_setprio(1);
#pragma unroll
    for (int c = 0; c < 4; ++c)
      cacc = __builtin_amdgcn_mfma_f32_32x32x16_bf16(kk[c], Qf[c], cacc, 0, 0, 0);
    __builtin_amdgcn_s_setprio(0);

    float p[16];
#pragma unroll
    for (int r = 0; r < 16; ++r) {
      int jrow = (r & 3) + 8 * (r >> 2) + 4 * hh;
      float bd = Wp[jrow - ql + 31][ql];
      float sc = (cacc[r] + bd) * 0.125f;
      float mv = (&mf4[r >> 2].x)[r & 3];
      float pv = mv * __expf(sc);
      p[r] = pv;
      l_acc += pv;
    }

#pragma unroll
    for (int g = 0; g < 4; ++g) {
      uint2 st;
      st.x = pk2(p[4 * g + 0], p[4 * g + 1]);
      st.y = pk2(p[4 * g + 2], p[4 * g + 3]);
      *reinterpret_cast<uint2*>(pbrow + j0 + 8 * g + 4 * hh) = st;
    }

#pragma unroll
    for (int kh = 0; kh < 2; ++kh) {
      unsigned int u0 = pk2(p[8 * kh + 0], p[8 * kh + 1]);
      unsigned int u1 = pk2(p[8 * kh + 2], p[8 * kh + 3]);
      unsigned int u2 = pk2(p[8 * kh + 4], p[8 * kh + 5]);
      unsigned int u3 = pk2(p[8 * kh + 6], p[8 * kh + 7]);
      unsigned int t0 = (unsigned int)__shfl_xor((int)u0, 32);
      unsigned int t1 = (unsigned int)__shfl_xor((int)u1, 32);
      unsigned int t2 = (unsigned int)__shfl_xor((int)u2, 32);
      unsigned int t3 = (unsigned int)__shfl_xor((int)u3, 32);
      unsigned int fr[4];
      fr[0] = hh ? t2 : u0;
      fr[1] = hh ? t3 : u1;
      fr[2] = hh ? u2 : t0;
      fr[3] = hh ? u3 : t1;
      bf16x8 pa = *reinterpret_cast<bf16x8*>(fr);
      __builtin_amdgcn_s_setprio(1);
      pacc0 = __builtin_amdgcn_mfma_f32_32x32x16_bf16(pa, kh ? v01 : v00, pacc0, 0, 0, 0);
      pacc1 = __builtin_amdgcn_mfma_f32_32x32x16_bf16(pa, kh ? v11 : v10, pacc1, 0, 0, 0);
      __builtin_amdgcn_s_setprio(0);
    }
  }

#pragma unroll
  for (int r = 0; r < 16; ++r) {
    int qrow = (r & 3) + 8 * (r >> 2) + 4 * hh;
    Wp[qrow][ql] = pacc0[r];
    Wp[32 + qrow][ql] = pacc1[r];
  }
  float lh = l_acc + __shfl_xor(l_acc, 32);
  if (lane < 32) sl[wv][ql] = lh;
  __syncthreads();

  if (wv < 2) {
    if (lane < 32) {
      float lt = sl[wv][ql] + sl[wv + 2][ql];
      linv[wv * 32 + ql] = 1.0f / lt;
    }
#pragma unroll
    for (int r = 0; r < 16; ++r) {
      int qrow = (r & 3) + 8 * (r >> 2) + 4 * hh;
      float lt = sl[wv][qrow] + sl[wv + 2][qrow];
      float iv = 1.0f / lt;
      float s0v = W[wv][qrow][ql] + W[wv + 2][qrow][ql];
      float s1v = W[wv][32 + qrow][ql] + W[wv + 2][32 + qrow][ql];
      size_t aoff = ((size_t)(q0 + qrow) * NB + b) * DMODEL + h * NDH;
      av_bf[aoff + ql] = f2bf(s0v * iv);
      av_bf[aoff + 32 + ql] = f2bf(s1v * iv);
    }
  }
  __syncthreads();

  const ushortT* probus = (const ushortT*)prob;
  const int lr = lane >> 4;
  const int cg = lane & 15;
  for (int s = 0; s < 8; ++s) {
    const int rloc = qtile * 32 + s * 4 + lr;
    const int rowg = blockIdx.x * 64 + rloc;
    const size_t ub = ((size_t)bh * TLEN + rowg) * 4096 + 2048 + jh * 1024 + cg * 8;
    const size_t fb = ((size_t)bh * TLEN + rowg) * 2048 + jh * 1024 + cg * 8;
    uint4 a[8];
#pragma unroll
    for (int k = 0; k < 8; ++k)
      a[k] = *reinterpret_cast<const uint4*>(probus + ub + k * 128);
    const float iv = linv[rloc];
    __syncthreads();
#pragma unroll
    for (int k = 0; k < 8; ++k) {
      float4 o0, o1;
      o0.x = bf2f((ushortT)(a[k].x & 0xffff)) * iv;
      o0.y = bf2f((ushortT)(a[k].x >> 16)) * iv;
      o0.z = bf2f((ushortT)(a[k].y & 0xffff)) * iv;
      o0.w = bf2f((ushortT)(a[k].y >> 16)) * iv;
      o1.x = bf2f((ushortT)(a[k].z & 0xffff)) * iv;
      o1.y = bf2f((ushortT)(a[k].z >> 16)) * iv;
      o1.z = bf2f((ushortT)(a[k].w & 0xffff)) * iv;
      o1.w = bf2f((ushortT)(a[k].w >> 16)) * iv;
      *reinterpret_cast<float4*>(prob + fb + k * 128) = o0;
      *reinterpret_cast<float4*>(prob + fb + k * 128 + 4) = o1;
    }
  }
}

// ---------------------------------------------------------------------------

extern "C" void kernel_launch(void* const* d_in, const int* in_sizes, int n_in,
                              void* d_out, int out_size, void* d_ws, size_t ws_size,
                              hipStream_t stream) {
  const float* w      = (const float*)d_in[0];   // (T,B,D)
  const float* r      = (const float*)d_in[1];   // (T,D)
  const float* w_qkv  = (const float*)d_in[2];   // (3072,1024)
  const float* w_r    = (const float*)d_in[3];   // (1024,1024)
  const float* w_o    = (const float*)d_in[4];   // (1024,1024)
  const float* bias   = (const float*)d_in[5];   // (16,64)
  const int* mask     = (const int*)d_in[6];     // (T,B) int32

  float* out  = (float*)d_out;
  float* prob = out + (size_t)TLEN * NB * DMODEL;

  const size_t SZ = (size_t)NB * NH * TLEN * NDH;        // 4194304
  ushortT* w_bf    = (ushortT*)d_ws;
  ushortT* wqkv_bf = w_bf + (size_t)4096 * 1024;
  ushortT* r_bf    = wqkv_bf + (size_t)3072 * 1024;
  ushortT* wr_bf   = r_bf + (size_t)2048 * 1024;
  ushortT* wo_bf   = wr_bf + (size_t)1024 * 1024;
  ushortT* q_bf    = wo_bf + (size_t)1024 * 1024;
  ushortT* k_bf    = q_bf + SZ;
  ushortT* vt_bf   = k_bf + SZ;
  ushortT* rkE_bf  = vt_bf + SZ;                         // 16*4096*64
  ushortT* av_bf   = rkE_bf + (size_t)NH * 4096 * NDH;
  float* mfl       = (float*)(av_bf + SZ);
  float* linv_g    = mfl + (size_t)NB * TLEN;
  unsigned int* S  = (unsigned int*)(linv_g + (size_t)NB * NH * TLEN);
  const size_t need = (size_t)((char*)(S + (size_t)NB * NH * (TLEN / 2) * TLEN) -
                               (char*)d_ws);
  const bool fast = ws_size >= need;

  // fused prologue: 2883584 float4 converts + 768 tail threads
  cvt_all<<<dim3((2883584 + 768 + 255) / 256), 256, 0, stream>>>(
      w, w_qkv, r, w_r, w_o, w_bf, wqkv_bf, r_bf, wr_bf, wo_bf, mask, mfl, rkE_bf);

  EpiQKV e1{q_bf, k_bf, vt_bf, bias};
  gemm_bf16<EpiQKV><<<dim3(3072 / 128, 4096 / 128), 256, 0, stream>>>(w_bf, wqkv_bf, DMODEL, e1);
  EpiRK e2{rkE_bf};
  gemm_bf16<EpiRK><<<dim3(1024 / 128, 2048 / 128), 256, 0, stream>>>(r_bf, wr_bf, DMODEL, e2);

  if (fast) {
    attn_fast<<<dim3(32, 32), 128, 0, stream>>>(q_bf, k_bf, vt_bf, rkE_bf,
                                                mfl, S, linv_g, av_bf);
    rescale_t<<<dim3(32, 16, 32), 256, 0, stream>>>(S, linv_g, prob);
  } else {
    attn_fused<<<dim3(32, 32), 256, 0, stream>>>(q_bf, k_bf, vt_bf, rkE_bf,
                                                 mfl, prob, av_bf);
  }

  EpiOut e5{out};
  gemm_bf16<EpiOut><<<dim3(1024 / 128, 4096 / 128), 256, 0, stream>>>(av_bf, wo_bf, DMODEL, e5);
}